// Round 1
// 726.248 us; speedup vs baseline: 1.0077x; 1.0077x over previous
//
#include <hip/hip_runtime.h>
#include <math.h>
#include <stdint.h>

#define B_Q    512
#define N_BANK 100000
#define D_DIM  256
#define K16    16

// ---------------- MFMA path constants ----------------
#define NSL2   256                          // j-slices for screen3 (grid = NSL2*4)
#define NCHUNK 1563                         // ceil(100000/64)
#define TROW   264                          // bf16 elems per padded row (256 + 8 pad)
#define CHUNK_USHORT (64 * TROW)            // 16896
#define CHUNK_BYTES  (CHUNK_USHORT * 2)     // 33792
#define NGRP   6250                         // 100000 / 16 j-groups per query
#define GSTRIDE 6272                        // padded group row stride (floats)
#define MARGIN 5e-3f                        // >= 2*eps_screen (worst-case bf16 dot bound)
#define CAPG   384                          // max surviving groups per query (exp ~30)

// ws layout (bytes)
#define OFF_QN     0                        // fp32 qn: 512KB
#define OFF_QNT    0x80000                  // bf16 tiled qn: 270336
#define OFF_INORM  0x100000                 // fp32 inorm: 400000
#define OFF_TH     0x170000                 // fp32 th[512]
#define OFF_GMAX   0x400000                 // fp32 gmax[512][6272] = 12.85MB (ends < 0x1400000)
#define OFF_BANKT  0x1400000                // bf16 tiled bank: 1563*33792
#define WS_NEED    ((size_t)OFF_BANKT + (size_t)NCHUNK * CHUNK_BYTES)

// fallback path ws layout
#define FB_OFF_INORM (B_Q * D_DIM * 4)
#define FB_OFF_PSC   (1024 * 1024)
#define FB_OFF_PID   (FB_OFF_PSC + B_Q * 128 * K16 * 4)

typedef __attribute__((ext_vector_type(8))) short short8;
typedef __attribute__((ext_vector_type(4))) float floatx4;

typedef __attribute__((address_space(1))) const unsigned char gu8_t;
typedef __attribute__((address_space(3))) unsigned char lu8_t;

// ---------------- helpers ----------------
__device__ inline unsigned short f2bf(float x) {   // RNE fp32 -> bf16
    unsigned int u = __float_as_uint(x);
    unsigned int r = (u + 0x7FFFu + ((u >> 16) & 1u)) >> 16;
    return (unsigned short)r;
}
__device__ inline unsigned long long pack_key(float s, int idx) {
    unsigned int u = __float_as_uint(s);
    u ^= (u & 0x80000000u) ? 0xFFFFFFFFu : 0x80000000u;  // order-preserving
    return ((unsigned long long)u << 32) | (unsigned int)(~(unsigned int)idx);
}
__device__ inline int key_idx(unsigned long long k) {
    return (int)(~(unsigned int)(k & 0xFFFFFFFFull));
}
__device__ inline unsigned long long shfl_down_u64(unsigned long long x, int off) {
    unsigned int lo = (unsigned int)x;
    unsigned int hi = (unsigned int)(x >> 32);
    lo = __shfl_down(lo, off, 64);
    hi = __shfl_down(hi, off, 64);
    return ((unsigned long long)hi << 32) | lo;
}
__device__ inline unsigned long long umax64(unsigned long long a, unsigned long long b) {
    return a > b ? a : b;
}

// ================= MFMA PATH =================

// qn = normalize(z_ego @ W^T) fp32, plus bf16 padded-tiled copy
__global__ void qn_prep_kernel(const float* __restrict__ z_ego,
                               const float* __restrict__ W,
                               float* __restrict__ qn,
                               unsigned short* __restrict__ qnt) {
    __shared__ float zs[D_DIM];
    __shared__ float red[4];
    int b = blockIdx.x;
    int t = threadIdx.x;
    zs[t] = z_ego[b * D_DIM + t];
    __syncthreads();
    const float4* W4 = reinterpret_cast<const float4*>(W + (size_t)t * D_DIM);
    float acc = 0.f;
#pragma unroll 8
    for (int u = 0; u < 64; ++u) {
        float4 w = W4[u];
        acc += w.x * zs[u * 4 + 0];
        acc += w.y * zs[u * 4 + 1];
        acc += w.z * zs[u * 4 + 2];
        acc += w.w * zs[u * 4 + 3];
    }
    float ss = acc * acc;
#pragma unroll
    for (int off = 32; off > 0; off >>= 1) ss += __shfl_down(ss, off, 64);
    if ((t & 63) == 0) red[t >> 6] = ss;
    __syncthreads();
    float tot = red[0] + red[1] + red[2] + red[3];
    float n = fmaxf(sqrtf(tot), 1e-12f);
    float v = acc / n;
    qn[b * D_DIM + t] = v;
    qnt[(size_t)(b >> 6) * CHUNK_USHORT + (size_t)(b & 63) * TROW + t] = f2bf(v);
}

// fused: row norms + bf16 normalized tiled bank
__global__ __launch_bounds__(256)
void prep_bank_kernel(const float* __restrict__ bank,
                      float* __restrict__ inorm,
                      unsigned short* __restrict__ bankt) {
    int c = blockIdx.x;
    int t = threadIdx.x, w = t >> 6, l = t & 63;
    unsigned short* dst = bankt + (size_t)c * CHUNK_USHORT;
#pragma unroll 1
    for (int rr = 0; rr < 16; ++rr) {
        int row = w * 16 + rr;
        int jg = c * 64 + row;
        ushort4 o = {0, 0, 0, 0};
        if (jg < N_BANK) {
            float4 v = *reinterpret_cast<const float4*>(bank + (size_t)jg * D_DIM + l * 4);
            float ss = v.x * v.x + v.y * v.y + v.z * v.z + v.w * v.w;
#pragma unroll
            for (int off = 1; off < 64; off <<= 1) ss += __shfl_xor(ss, off, 64);
            float inv = 1.0f / fmaxf(sqrtf(ss), 1e-12f);
            o.x = f2bf(v.x * inv); o.y = f2bf(v.y * inv);
            o.z = f2bf(v.z * inv); o.w = f2bf(v.w * inv);
            if (l == 0) inorm[jg] = inv;
        }
        *reinterpret_cast<ushort4*>(dst + (size_t)row * TROW + l * 4) = o;
    }
}

// screen3: 128-query blocks, LDS-staged bank chunk, svt software pipeline.
// Per block: 4 waves x 32 queries; chunk (64 j) staged once into LDS via
// global_load_lds (dense lines), each wave sweeps all 4 j-groups from LDS.
// bankt L2/L3 traffic drops 4x vs screen2; identical arithmetic -> identical gmax.
__global__ __launch_bounds__(256, 4)
void screen3_kernel(const unsigned short* __restrict__ qnt,
                    const unsigned short* __restrict__ bankt,
                    const float* __restrict__ svt,
                    float* __restrict__ gmax) {
    __shared__ unsigned short lbank[CHUNK_USHORT];   // 33792 B
    int t = threadIdx.x, w = t >> 6, l = t & 63;
    int lane16 = l & 15, quad = l >> 4;

    // bid remap: 4 q-blocks of the same slice land on the same XCD (bid%8),
    // adjacent in launch order -> chunk L2-resident for the later three.
    int bid = blockIdx.x;
    int xcd = bid & 7;
    int t2 = bid >> 3;
    int qb = t2 & 3;                     // q-block 0..3 (128 queries each)
    int slice = xcd + 8 * (t2 >> 2);     // 0..255

    int qt = qb * 4 + w;                 // this wave's 32-query tile (0..15)
    int qbase = qt * 32;

    // A-fragments (32 queries x 256 k) -> AGPR-resident
    short8 afrag[2][8];
    {
        const unsigned short* abase = qnt + (size_t)(qt >> 1) * CHUNK_USHORT
                                          + (size_t)((qt & 1) * 32) * TROW;
#pragma unroll
        for (int s = 0; s < 2; ++s)
#pragma unroll
            for (int k = 0; k < 8; ++k)
                afrag[s][k] = *reinterpret_cast<const short8*>(
                    abase + (size_t)(16 * s + lane16) * TROW + k * 32 + quad * 8);
    }

    // per-(s,r) svt row pointers for this lane's 8 query rows (hoists 64-bit muls)
    const float* svr[2][4];
#pragma unroll
    for (int s = 0; s < 2; ++s)
#pragma unroll
        for (int r = 0; r < 4; ++r)
            svr[s][r] = svt + (size_t)(qbase + 16 * s + 4 * quad + r) * (size_t)N_BANK;

    for (int c = slice; c < NCHUNK; c += NSL2) {
        int j0 = c * 64;

        // ---- stage chunk into LDS (dense, async). Each wave covers 1KB per call.
        {
            const unsigned char* gsrc = (const unsigned char*)bankt + (size_t)c * CHUNK_BYTES;
            unsigned char* lbase = (unsigned char*)lbank;
#pragma unroll
            for (int i = 0; i < 8; ++i) {
                int off = i * 4096 + w * 1024;
                __builtin_amdgcn_global_load_lds((gu8_t*)(gsrc + off + l * 16),
                                                 (lu8_t*)(lbase + off), 16, 0, 0);
            }
            int off8 = 32768 + w * 256;  // tail 1024B, 4B per lane
            __builtin_amdgcn_global_load_lds((gu8_t*)(gsrc + off8 + l * 4),
                                             (lu8_t*)(lbase + off8), 4, 0, 0);
        }

        // ---- prefetch svt for jg=0 (overlaps staging wait)
        float sv_cur[2][4], sv_nxt[2][4];
        {
            int jglob = j0 + lane16;
            bool inb = jglob < N_BANK;
#pragma unroll
            for (int s = 0; s < 2; ++s)
#pragma unroll
                for (int r = 0; r < 4; ++r)
                    sv_cur[s][r] = inb ? svr[s][r][jglob] : 0.f;
        }

        __syncthreads();   // staging + sv0 complete

        int g0 = c * 4;
#pragma unroll
        for (int jg = 0; jg < 4; ++jg) {
            // prefetch next j-group's svt under this group's MFMA
            if (jg < 3) {
                int jglob = j0 + 16 * (jg + 1) + lane16;
                bool inb = jglob < N_BANK;
#pragma unroll
                for (int s = 0; s < 2; ++s)
#pragma unroll
                    for (int r = 0; r < 4; ++r)
                        sv_nxt[s][r] = inb ? svr[s][r][jglob] : 0.f;
            }

            floatx4 acc0 = (floatx4){0.f, 0.f, 0.f, 0.f};
            floatx4 acc1 = (floatx4){0.f, 0.f, 0.f, 0.f};
            const unsigned short* bbase = lbank + (size_t)(16 * jg + lane16) * TROW + quad * 8;
#pragma unroll
            for (int k = 0; k < 8; ++k) {
                short8 bfrag = *reinterpret_cast<const short8*>(bbase + k * 32);
                acc0 = __builtin_amdgcn_mfma_f32_16x16x32_bf16(afrag[0][k], bfrag, acc0, 0, 0, 0);
                acc1 = __builtin_amdgcn_mfma_f32_16x16x32_bf16(afrag[1][k], bfrag, acc1, 0, 0, 0);
            }

            int jglob = j0 + 16 * jg + lane16;
            bool inb = jglob < N_BANK;
            int g = g0 + jg;
            bool doStore = (lane16 == 0) && (g < NGRP);
#pragma unroll
            for (int s = 0; s < 2; ++s) {
#pragma unroll
                for (int r = 0; r < 4; ++r) {
                    float a = (s == 0) ? acc0[r] : acc1[r];
                    float score = inb ? (0.5f * a + 0.5f * sv_cur[s][r]) : -INFINITY;
                    // max over the 16 j's (lane16 bits 0..3)
                    score = fmaxf(score, __shfl_xor(score, 1, 64));
                    score = fmaxf(score, __shfl_xor(score, 2, 64));
                    score = fmaxf(score, __shfl_xor(score, 4, 64));
                    score = fmaxf(score, __shfl_xor(score, 8, 64));
                    if (doStore) {
                        int q = qbase + 16 * s + 4 * quad + r;
                        gmax[(size_t)q * GSTRIDE + g] = score;
                    }
                }
            }

            if (jg < 3) {
#pragma unroll
                for (int s = 0; s < 2; ++s)
#pragma unroll
                    for (int r = 0; r < 4; ++r)
                        sv_cur[s][r] = sv_nxt[s][r];
            }
        }
        __syncthreads();   // protect lbank before next chunk's staging
    }
}

// per-query: 16th-largest group-max - margin -> th
__global__ __launch_bounds__(256)
void gthresh_kernel(const float* __restrict__ gmax,
                    float* __restrict__ th) {
    __shared__ float buf[NGRP];    // 25 KB
    __shared__ float red[4];
    int q = blockIdx.x, t = threadIdx.x, w = t >> 6;
    for (int i = t; i < NGRP; i += 256) buf[i] = gmax[(size_t)q * GSTRIDE + i];
    __syncthreads();
    float s16 = -INFINITY;
    for (int r = 0; r < K16; ++r) {
        float m = -INFINITY;
        for (int i = t; i < NGRP; i += 256) m = fmaxf(m, buf[i]);
#pragma unroll
        for (int off = 32; off > 0; off >>= 1) m = fmaxf(m, __shfl_down(m, off, 64));
        if ((t & 63) == 0) red[w] = m;
        __syncthreads();
        m = fmaxf(fmaxf(red[0], red[1]), fmaxf(red[2], red[3]));
        if (r == K16 - 1) s16 = m;
        if (r < K16 - 1) {
            for (int i = t; i < NGRP; i += 256)
                if (buf[i] == m) buf[i] = -INFINITY;
        }
        __syncthreads();
    }
    if (t == 0) th[q] = s16 - MARGIN;
}

// per-query: collect groups >= th, exact fp32 rescore of members, top-16, gather
__global__ __launch_bounds__(256)
void grescore_kernel(const float* __restrict__ gmax,
                     const float* __restrict__ th,
                     const float* __restrict__ qn,
                     const float* __restrict__ inorm,
                     const float* __restrict__ bank,
                     const float* __restrict__ svt,
                     float* __restrict__ out) {
    __shared__ float qns[D_DIM];
    __shared__ int glist[CAPG];
    __shared__ unsigned long long keys2[CAPG * K16];   // 48 KB
    __shared__ unsigned long long wred[4];
    __shared__ int winI[K16];
    __shared__ int gcntS;
    int b = blockIdx.x, t = threadIdx.x;
    int w = t >> 6, l = t & 63;

    qns[t] = qn[(size_t)b * D_DIM + t];
    if (t == 0) gcntS = 0;
    __syncthreads();
    float thb = th[b];
    for (int g = t; g < NGRP; g += 256) {
        if (gmax[(size_t)b * GSTRIDE + g] >= thb) {
            int p = atomicAdd(&gcntS, 1);
            if (p < CAPG) glist[p] = g;
        }
    }
    __syncthreads();
    int ng = gcntS < CAPG ? gcntS : CAPG;
    int ncand = ng * K16;

    const float4* bank4 = reinterpret_cast<const float4*>(bank);
    float4 qv = reinterpret_cast<const float4*>(qns)[l];
    for (int ci = w; ci < ncand; ci += 4) {
        int j = glist[ci >> 4] * K16 + (ci & 15);
        float4 bv = bank4[(size_t)j * 64 + l];
        float d = qv.x * bv.x + qv.y * bv.y + qv.z * bv.z + qv.w * bv.w;
#pragma unroll
        for (int off = 32; off > 0; off >>= 1) d += __shfl_down(d, off, 64);
        if (l == 0) {
            float score = 0.5f * (d * inorm[j]) + 0.5f * svt[(size_t)b * N_BANK + j];
            keys2[ci] = pack_key(score, j);
        }
    }
    __syncthreads();

    for (int r = 0; r < K16; ++r) {
        unsigned long long best = 0ull;
        for (int i = t; i < ncand; i += 256) best = umax64(best, keys2[i]);
#pragma unroll
        for (int off = 32; off > 0; off >>= 1) best = umax64(best, shfl_down_u64(best, off));
        if (l == 0) wred[w] = best;
        __syncthreads();
        unsigned long long W = umax64(umax64(wred[0], wred[1]), umax64(wred[2], wred[3]));
        if (t == 0) winI[r] = key_idx(W);
        for (int i = t; i < ncand; i += 256)
            if (keys2[i] == W) keys2[i] = 0ull;
        __syncthreads();
    }

    if (t < K16)
        out[(size_t)B_Q * K16 * D_DIM + (size_t)b * K16 + t] = (float)winI[t];
    float4* out4 = reinterpret_cast<float4*>(out);
    for (int u = t; u < K16 * 64; u += 256) {
        int r = u >> 6, cc = u & 63;
        out4[((size_t)b * K16 + r) * 64 + cc] = bank4[(size_t)winI[r] * 64 + cc];
    }
}

// ================= FALLBACK (verified round-1) PATH =================
#define FBT 64
#define FJT 64
#define FKC 64
#define FNS 128
#define FNC ((N_BANK + FJT - 1) / FJT)

__global__ void inorm_kernel(const float* __restrict__ bank,
                             float* __restrict__ inorm) {
    int w = threadIdx.x >> 6;
    int lane = threadIdx.x & 63;
    int j = blockIdx.x * 4 + w;
    if (j >= N_BANK) return;
    const float4* r4 = reinterpret_cast<const float4*>(bank + (size_t)j * D_DIM);
    float4 v = r4[lane];
    float ss = v.x * v.x + v.y * v.y + v.z * v.z + v.w * v.w;
#pragma unroll
    for (int off = 32; off > 0; off >>= 1) ss += __shfl_down(ss, off, 64);
    if (lane == 0) inorm[j] = 1.0f / fmaxf(sqrtf(ss), 1e-12f);
}

__global__ void fb_qn_kernel(const float* __restrict__ z_ego,
                             const float* __restrict__ W,
                             float* __restrict__ qn) {
    __shared__ float zs[D_DIM];
    __shared__ float red[4];
    int b = blockIdx.x;
    int t = threadIdx.x;
    zs[t] = z_ego[b * D_DIM + t];
    __syncthreads();
    const float4* W4 = reinterpret_cast<const float4*>(W + (size_t)t * D_DIM);
    float acc = 0.f;
#pragma unroll 8
    for (int u = 0; u < 64; ++u) {
        float4 w = W4[u];
        acc += w.x * zs[u * 4 + 0]; acc += w.y * zs[u * 4 + 1];
        acc += w.z * zs[u * 4 + 2]; acc += w.w * zs[u * 4 + 3];
    }
    float ss = acc * acc;
#pragma unroll
    for (int off = 32; off > 0; off >>= 1) ss += __shfl_down(ss, off, 64);
    if ((t & 63) == 0) red[t >> 6] = ss;
    __syncthreads();
    float tot = red[0] + red[1] + red[2] + red[3];
    qn[b * D_DIM + t] = acc / fmaxf(sqrtf(tot), 1e-12f);
}

__global__ __launch_bounds__(256)
void fb_score_topk_kernel(const float* __restrict__ qn,
                          const float* __restrict__ bank,
                          const float* __restrict__ svt,
                          const float* __restrict__ inorm,
                          float* __restrict__ psc,
                          int* __restrict__ pid) {
    __shared__ float As[FKC][FBT];
    __shared__ float Bsh[FKC][FJT];
    __shared__ float Ss[FBT][FJT + 1];
    int slice = blockIdx.x;
    int qbase = blockIdx.y * FBT;
    int t = threadIdx.x;
    int tq = t >> 4, tj = t & 15;
    int q0 = tq * 4, j0l = tj * 4;
    float sc[K16]; int id[K16];
#pragma unroll
    for (int i = 0; i < K16; ++i) { sc[i] = -INFINITY; id[i] = 0x7fffffff; }
    for (int c = slice; c < FNC; c += FNS) {
        int j0 = c * FJT;
        float acc[4][4];
#pragma unroll
        for (int a = 0; a < 4; ++a)
#pragma unroll
            for (int b2 = 0; b2 < 4; ++b2) acc[a][b2] = 0.f;
        for (int kc = 0; kc < D_DIM; kc += FKC) {
            __syncthreads();
#pragma unroll
            for (int r = 0; r < 4; ++r) {
                int idx = t + 256 * r;
                int q = idx & 63, kv = idx >> 6;
                float4 v = *reinterpret_cast<const float4*>(
                    &qn[(size_t)(qbase + q) * D_DIM + kc + kv * 4]);
                As[kv * 4 + 0][q] = v.x; As[kv * 4 + 1][q] = v.y;
                As[kv * 4 + 2][q] = v.z; As[kv * 4 + 3][q] = v.w;
            }
#pragma unroll
            for (int r = 0; r < 4; ++r) {
                int idx = t + 256 * r;
                int j = idx & 63, kv = idx >> 6;
                int jg = j0 + j;
                float4 v = make_float4(0.f, 0.f, 0.f, 0.f);
                if (jg < N_BANK)
                    v = *reinterpret_cast<const float4*>(
                        &bank[(size_t)jg * D_DIM + kc + kv * 4]);
                Bsh[kv * 4 + 0][j] = v.x; Bsh[kv * 4 + 1][j] = v.y;
                Bsh[kv * 4 + 2][j] = v.z; Bsh[kv * 4 + 3][j] = v.w;
            }
            __syncthreads();
#pragma unroll
            for (int k = 0; k < FKC; ++k) {
                float4 av = *reinterpret_cast<const float4*>(&As[k][q0]);
                float4 bv = *reinterpret_cast<const float4*>(&Bsh[k][j0l]);
                float a[4] = {av.x, av.y, av.z, av.w};
                float bb[4] = {bv.x, bv.y, bv.z, bv.w};
#pragma unroll
                for (int qi = 0; qi < 4; ++qi)
#pragma unroll
                    for (int ji = 0; ji < 4; ++ji) acc[qi][ji] += a[qi] * bb[ji];
            }
        }
        bool full = (j0 + FJT <= N_BANK);
        if (full) {
            float4 inv = *reinterpret_cast<const float4*>(&inorm[j0 + j0l]);
            float iv[4] = {inv.x, inv.y, inv.z, inv.w};
#pragma unroll
            for (int qi = 0; qi < 4; ++qi) {
                int q = qbase + q0 + qi;
                float4 svv = *reinterpret_cast<const float4*>(
                    &svt[(size_t)q * N_BANK + j0 + j0l]);
                float s[4] = {svv.x, svv.y, svv.z, svv.w};
#pragma unroll
                for (int ji = 0; ji < 4; ++ji)
                    Ss[q0 + qi][j0l + ji] = 0.5f * (acc[qi][ji] * iv[ji]) + 0.5f * s[ji];
            }
        } else {
#pragma unroll
            for (int qi = 0; qi < 4; ++qi) {
                int q = qbase + q0 + qi;
#pragma unroll
                for (int ji = 0; ji < 4; ++ji) {
                    int jg = j0 + j0l + ji;
                    float s = -INFINITY;
                    if (jg < N_BANK)
                        s = 0.5f * (acc[qi][ji] * inorm[jg]) + 0.5f * svt[(size_t)q * N_BANK + jg];
                    Ss[q0 + qi][j0l + ji] = s;
                }
            }
        }
        __syncthreads();
        if (t < FBT) {
#pragma unroll 1
            for (int jj = 0; jj < FJT; ++jj) {
                int jg = j0 + jj;
                if (jg >= N_BANK) break;
                float s = Ss[t][jj];
                if (s > sc[K16 - 1] || (s == sc[K16 - 1] && jg < id[K16 - 1])) {
                    float cs = s; int ci = jg;
#pragma unroll
                    for (int i = 0; i < K16; ++i) {
                        bool bt2 = (cs > sc[i]) || (cs == sc[i] && ci < id[i]);
                        float ts = sc[i]; int ti = id[i];
                        if (bt2) { sc[i] = cs; id[i] = ci; cs = ts; ci = ti; }
                    }
                }
            }
        }
    }
    if (t < FBT) {
        int q = qbase + t;
        size_t base = ((size_t)q * FNS + slice) * K16;
#pragma unroll
        for (int i = 0; i < K16; ++i) { psc[base + i] = sc[i]; pid[base + i] = id[i]; }
    }
}

__global__ __launch_bounds__(256)
void fb_merge_kernel(const float* __restrict__ psc,
                     const int* __restrict__ pid,
                     const float* __restrict__ bank,
                     float* __restrict__ out) {
    __shared__ unsigned long long keys[FNS * K16];
    __shared__ unsigned long long wred[4];
    __shared__ int win[K16];
    int b = blockIdx.x, t = threadIdx.x;
    for (int i = t; i < FNS * K16; i += 256) {
        float s = psc[(size_t)b * FNS * K16 + i];
        unsigned int u = __float_as_uint(s);
        u ^= (u & 0x80000000u) ? 0xFFFFFFFFu : 0x80000000u;
        unsigned int iv = ~(unsigned int)pid[(size_t)b * FNS * K16 + i];
        keys[i] = ((unsigned long long)u << 32) | iv;
    }
    __syncthreads();
    for (int r = 0; r < K16; ++r) {
        unsigned long long best = 0ull;
        for (int i = t; i < FNS * K16; i += 256) best = umax64(best, keys[i]);
#pragma unroll
        for (int off = 32; off > 0; off >>= 1) best = umax64(best, shfl_down_u64(best, off));
        if ((t & 63) == 0) wred[t >> 6] = best;
        __syncthreads();
        unsigned long long w = umax64(umax64(wred[0], wred[1]), umax64(wred[2], wred[3]));
        if (t == 0) win[r] = (int)(~(unsigned int)w);
        for (int i = t; i < FNS * K16; i += 256)
            if (keys[i] == w) keys[i] = 0ull;
        __syncthreads();
    }
    if (t < K16)
        out[(size_t)B_Q * K16 * D_DIM + (size_t)b * K16 + t] = (float)win[t];
    const float4* bank4 = reinterpret_cast<const float4*>(bank);
    float4* out4 = reinterpret_cast<float4*>(out);
    for (int u = t; u < K16 * 64; u += 256) {
        int r = u >> 6, c = u & 63;
        out4[((size_t)b * K16 + r) * 64 + c] = bank4[(size_t)win[r] * 64 + c];
    }
}

// ---------------- launcher ----------------
extern "C" void kernel_launch(void* const* d_in, const int* in_sizes, int n_in,
                              void* d_out, int out_size, void* d_ws, size_t ws_size,
                              hipStream_t stream) {
    const float* z_ego = (const float*)d_in[0];
    const float* bank  = (const float*)d_in[1];
    const float* svt   = (const float*)d_in[2];
    const float* W     = (const float*)d_in[3];
    float* out = (float*)d_out;
    char* ws = (char*)d_ws;

    if (ws_size >= WS_NEED) {
        float* qn             = (float*)(ws + OFF_QN);
        unsigned short* qnt   = (unsigned short*)(ws + OFF_QNT);
        float* inorm          = (float*)(ws + OFF_INORM);
        float* th             = (float*)(ws + OFF_TH);
        float* gmax           = (float*)(ws + OFF_GMAX);
        unsigned short* bankt = (unsigned short*)(ws + OFF_BANKT);

        qn_prep_kernel<<<B_Q, 256, 0, stream>>>(z_ego, W, qn, qnt);
        prep_bank_kernel<<<NCHUNK, 256, 0, stream>>>(bank, inorm, bankt);
        screen3_kernel<<<NSL2 * 4, 256, 0, stream>>>(qnt, bankt, svt, gmax);
        gthresh_kernel<<<B_Q, 256, 0, stream>>>(gmax, th);
        grescore_kernel<<<B_Q, 256, 0, stream>>>(gmax, th, qn, inorm, bank, svt, out);
    } else {
        float* qn    = (float*)(ws + 0);
        float* inorm = (float*)(ws + FB_OFF_INORM);
        float* psc   = (float*)(ws + FB_OFF_PSC);
        int*   pid   = (int*)(ws + FB_OFF_PID);
        fb_qn_kernel<<<B_Q, 256, 0, stream>>>(z_ego, W, qn);
        inorm_kernel<<<(N_BANK + 3) / 4, 256, 0, stream>>>(bank, inorm);
        dim3 grid(FNS, B_Q / FBT);
        fb_score_topk_kernel<<<grid, 256, 0, stream>>>(qn, bank, svt, inorm, psc, pid);
        fb_merge_kernel<<<B_Q, 256, 0, stream>>>(psc, pid, bank, out);
    }
}

// Round 2
// 698.747 us; speedup vs baseline: 1.0474x; 1.0394x over previous
//
#include <hip/hip_runtime.h>
#include <math.h>
#include <stdint.h>

#define B_Q    512
#define N_BANK 100000
#define D_DIM  256
#define K16    16

// ---------------- MFMA path constants ----------------
#define NSL2   256                          // j-slices for screen4 (grid = NSL2*4)
#define NCHUNK 1563                         // ceil(100000/64)
#define TROW   264                          // bf16 elems per padded row (256 + 8 pad)
#define CHUNK_USHORT (64 * TROW)            // 16896
#define CHUNK_BYTES  (CHUNK_USHORT * 2)     // 33792
#define NGRP   6250                         // 100000 / 16 j-groups per query
#define GSTRIDE 6272                        // padded group row stride (floats)
#define MARGIN 5e-3f                        // >= 2*eps_screen (worst-case bf16 dot bound)
#define CAPG   384                          // max surviving groups per query (exp ~30)

// ws layout (bytes)
#define OFF_QN     0                        // fp32 qn: 512KB
#define OFF_QNT    0x80000                  // bf16 tiled qn: 270336
#define OFF_INORM  0x100000                 // fp32 inorm: 400000
#define OFF_TH     0x170000                 // fp32 th[512]
#define OFF_GMAX   0x400000                 // fp32 gmax[512][6272] = 12.85MB (ends < 0x1400000)
#define OFF_BANKT  0x1400000                // bf16 tiled bank: 1563*33792
#define WS_NEED    ((size_t)OFF_BANKT + (size_t)NCHUNK * CHUNK_BYTES)

// fallback path ws layout
#define FB_OFF_INORM (B_Q * D_DIM * 4)
#define FB_OFF_PSC   (1024 * 1024)
#define FB_OFF_PID   (FB_OFF_PSC + B_Q * 128 * K16 * 4)

typedef __attribute__((ext_vector_type(8))) short short8;
typedef __attribute__((ext_vector_type(4))) float floatx4;

typedef __attribute__((address_space(1))) const unsigned char gu8_t;
typedef __attribute__((address_space(3))) unsigned char lu8_t;

// ---------------- helpers ----------------
__device__ inline unsigned short f2bf(float x) {   // RNE fp32 -> bf16
    unsigned int u = __float_as_uint(x);
    unsigned int r = (u + 0x7FFFu + ((u >> 16) & 1u)) >> 16;
    return (unsigned short)r;
}
__device__ inline unsigned long long pack_key(float s, int idx) {
    unsigned int u = __float_as_uint(s);
    u ^= (u & 0x80000000u) ? 0xFFFFFFFFu : 0x80000000u;  // order-preserving
    return ((unsigned long long)u << 32) | (unsigned int)(~(unsigned int)idx);
}
__device__ inline int key_idx(unsigned long long k) {
    return (int)(~(unsigned int)(k & 0xFFFFFFFFull));
}
__device__ inline unsigned long long shfl_down_u64(unsigned long long x, int off) {
    unsigned int lo = (unsigned int)x;
    unsigned int hi = (unsigned int)(x >> 32);
    lo = __shfl_down(lo, off, 64);
    hi = __shfl_down(hi, off, 64);
    return ((unsigned long long)hi << 32) | lo;
}
__device__ inline unsigned long long umax64(unsigned long long a, unsigned long long b) {
    return a > b ? a : b;
}

// ================= MFMA PATH =================

// qn = normalize(z_ego @ W^T) fp32, plus bf16 padded-tiled copy
__global__ void qn_prep_kernel(const float* __restrict__ z_ego,
                               const float* __restrict__ W,
                               float* __restrict__ qn,
                               unsigned short* __restrict__ qnt) {
    __shared__ float zs[D_DIM];
    __shared__ float red[4];
    int b = blockIdx.x;
    int t = threadIdx.x;
    zs[t] = z_ego[b * D_DIM + t];
    __syncthreads();
    const float4* W4 = reinterpret_cast<const float4*>(W + (size_t)t * D_DIM);
    float acc = 0.f;
#pragma unroll 8
    for (int u = 0; u < 64; ++u) {
        float4 w = W4[u];
        acc += w.x * zs[u * 4 + 0];
        acc += w.y * zs[u * 4 + 1];
        acc += w.z * zs[u * 4 + 2];
        acc += w.w * zs[u * 4 + 3];
    }
    float ss = acc * acc;
#pragma unroll
    for (int off = 32; off > 0; off >>= 1) ss += __shfl_down(ss, off, 64);
    if ((t & 63) == 0) red[t >> 6] = ss;
    __syncthreads();
    float tot = red[0] + red[1] + red[2] + red[3];
    float n = fmaxf(sqrtf(tot), 1e-12f);
    float v = acc / n;
    qn[b * D_DIM + t] = v;
    qnt[(size_t)(b >> 6) * CHUNK_USHORT + (size_t)(b & 63) * TROW + t] = f2bf(v);
}

// fused: row norms + bf16 normalized tiled bank
__global__ __launch_bounds__(256)
void prep_bank_kernel(const float* __restrict__ bank,
                      float* __restrict__ inorm,
                      unsigned short* __restrict__ bankt) {
    int c = blockIdx.x;
    int t = threadIdx.x, w = t >> 6, l = t & 63;
    unsigned short* dst = bankt + (size_t)c * CHUNK_USHORT;
#pragma unroll 1
    for (int rr = 0; rr < 16; ++rr) {
        int row = w * 16 + rr;
        int jg = c * 64 + row;
        ushort4 o = {0, 0, 0, 0};
        if (jg < N_BANK) {
            float4 v = *reinterpret_cast<const float4*>(bank + (size_t)jg * D_DIM + l * 4);
            float ss = v.x * v.x + v.y * v.y + v.z * v.z + v.w * v.w;
#pragma unroll
            for (int off = 1; off < 64; off <<= 1) ss += __shfl_xor(ss, off, 64);
            float inv = 1.0f / fmaxf(sqrtf(ss), 1e-12f);
            o.x = f2bf(v.x * inv); o.y = f2bf(v.y * inv);
            o.z = f2bf(v.z * inv); o.w = f2bf(v.w * inv);
            if (l == 0) inorm[jg] = inv;
        }
        *reinterpret_cast<ushort4*>(dst + (size_t)row * TROW + l * 4) = o;
    }
}

// screen4: XCD-contiguous slice mapping + chunk-batched svt reads.
//  - each XCD owns 32 contiguous slices (gmax lines g=4c..4c+15 stay in one L2;
//    bankt chunk fetched from HBM once into one XCD's L2, shared by its 4 q-blocks)
//  - all 32 svt values per lane loaded up-front: the 4x64B lines of one query row
//    are requested back-to-back (256B DRAM runs, 4x fewer row activates, 4x MLP)
// Arithmetic identical to screen3 -> identical gmax.
__global__ __launch_bounds__(256, 4)
void screen4_kernel(const unsigned short* __restrict__ qnt,
                    const unsigned short* __restrict__ bankt,
                    const float* __restrict__ svt,
                    float* __restrict__ gmax) {
    __shared__ unsigned short lbank[CHUNK_USHORT];   // 33792 B
    int t = threadIdx.x, w = t >> 6, l = t & 63;
    int lane16 = l & 15, quad = l >> 4;

    // bid -> (slice, qb): XCD (bid&7) owns slices [32*xcd, 32*xcd+31];
    // the 4 q-blocks of one slice are consecutive bids on the same XCD.
    int bid = blockIdx.x;
    int xcd = bid & 7;
    int i = bid >> 3;                    // 0..127
    int slice = (xcd << 5) + (i >> 2);   // 0..255
    int qb = i & 3;                      // q-block 0..3 (128 queries each)

    int qt = qb * 4 + w;                 // this wave's 32-query tile (0..15)
    int qbase = qt * 32;

    // A-fragments (32 queries x 256 k) -> AGPR-resident
    short8 afrag[2][8];
    {
        const unsigned short* abase = qnt + (size_t)(qt >> 1) * CHUNK_USHORT
                                          + (size_t)((qt & 1) * 32) * TROW;
#pragma unroll
        for (int s = 0; s < 2; ++s)
#pragma unroll
            for (int k = 0; k < 8; ++k)
                afrag[s][k] = *reinterpret_cast<const short8*>(
                    abase + (size_t)(16 * s + lane16) * TROW + k * 32 + quad * 8);
    }

    // per-(s,r) svt row pointers for this lane's 8 query rows
    const float* svr[2][4];
#pragma unroll
    for (int s = 0; s < 2; ++s)
#pragma unroll
        for (int r = 0; r < 4; ++r)
            svr[s][r] = svt + (size_t)(qbase + 16 * s + 4 * quad + r) * (size_t)N_BANK;

    for (int c = slice; c < NCHUNK; c += NSL2) {
        int j0 = c * 64;

        // ---- stage chunk into LDS (dense, async). Each wave covers 1KB per call.
        {
            const unsigned char* gsrc = (const unsigned char*)bankt + (size_t)c * CHUNK_BYTES;
            unsigned char* lbase = (unsigned char*)lbank;
#pragma unroll
            for (int i2 = 0; i2 < 8; ++i2) {
                int off = i2 * 4096 + w * 1024;
                __builtin_amdgcn_global_load_lds((gu8_t*)(gsrc + off + l * 16),
                                                 (lu8_t*)(lbase + off), 16, 0, 0);
            }
            int off8 = 32768 + w * 256;  // tail 1024B, 4B per lane
            __builtin_amdgcn_global_load_lds((gu8_t*)(gsrc + off8 + l * 4),
                                             (lu8_t*)(lbase + off8), 4, 0, 0);
        }

        // ---- batched svt loads for the whole chunk: per (s,r) row the 4 jg
        // lines are issued back-to-back (one 256B sequential DRAM run).
        float sv[4][2][4];
#pragma unroll
        for (int s = 0; s < 2; ++s)
#pragma unroll
            for (int r = 0; r < 4; ++r) {
                const float* rp = svr[s][r] + j0 + lane16;
#pragma unroll
                for (int jg = 0; jg < 4; ++jg) {
                    int jglob = j0 + 16 * jg + lane16;
                    sv[jg][s][r] = (jglob < N_BANK) ? rp[16 * jg] : 0.f;
                }
            }

        __syncthreads();   // staging + svt complete

        int g0 = c * 4;
#pragma unroll
        for (int jg = 0; jg < 4; ++jg) {
            floatx4 acc0 = (floatx4){0.f, 0.f, 0.f, 0.f};
            floatx4 acc1 = (floatx4){0.f, 0.f, 0.f, 0.f};
            const unsigned short* bbase = lbank + (size_t)(16 * jg + lane16) * TROW + quad * 8;
#pragma unroll
            for (int k = 0; k < 8; ++k) {
                short8 bfrag = *reinterpret_cast<const short8*>(bbase + k * 32);
                acc0 = __builtin_amdgcn_mfma_f32_16x16x32_bf16(afrag[0][k], bfrag, acc0, 0, 0, 0);
                acc1 = __builtin_amdgcn_mfma_f32_16x16x32_bf16(afrag[1][k], bfrag, acc1, 0, 0, 0);
            }

            int jglob = j0 + 16 * jg + lane16;
            bool inb = jglob < N_BANK;
            int g = g0 + jg;
            bool doStore = (lane16 == 0) && (g < NGRP);
#pragma unroll
            for (int s = 0; s < 2; ++s) {
#pragma unroll
                for (int r = 0; r < 4; ++r) {
                    float a = (s == 0) ? acc0[r] : acc1[r];
                    float score = inb ? (0.5f * a + 0.5f * sv[jg][s][r]) : -INFINITY;
                    // max over the 16 j's (lane16 bits 0..3)
                    score = fmaxf(score, __shfl_xor(score, 1, 64));
                    score = fmaxf(score, __shfl_xor(score, 2, 64));
                    score = fmaxf(score, __shfl_xor(score, 4, 64));
                    score = fmaxf(score, __shfl_xor(score, 8, 64));
                    if (doStore) {
                        int q = qbase + 16 * s + 4 * quad + r;
                        gmax[(size_t)q * GSTRIDE + g] = score;
                    }
                }
            }
        }
        __syncthreads();   // protect lbank before next chunk's staging
    }
}

// per-query: 16th-largest group-max - margin -> th
__global__ __launch_bounds__(256)
void gthresh_kernel(const float* __restrict__ gmax,
                    float* __restrict__ th) {
    __shared__ float buf[NGRP];    // 25 KB
    __shared__ float red[4];
    int q = blockIdx.x, t = threadIdx.x, w = t >> 6;
    for (int i = t; i < NGRP; i += 256) buf[i] = gmax[(size_t)q * GSTRIDE + i];
    __syncthreads();
    float s16 = -INFINITY;
    for (int r = 0; r < K16; ++r) {
        float m = -INFINITY;
        for (int i = t; i < NGRP; i += 256) m = fmaxf(m, buf[i]);
#pragma unroll
        for (int off = 32; off > 0; off >>= 1) m = fmaxf(m, __shfl_down(m, off, 64));
        if ((t & 63) == 0) red[w] = m;
        __syncthreads();
        m = fmaxf(fmaxf(red[0], red[1]), fmaxf(red[2], red[3]));
        if (r == K16 - 1) s16 = m;
        if (r < K16 - 1) {
            for (int i = t; i < NGRP; i += 256)
                if (buf[i] == m) buf[i] = -INFINITY;
        }
        __syncthreads();
    }
    if (t == 0) th[q] = s16 - MARGIN;
}

// per-query: collect groups >= th, exact fp32 rescore of members, top-16, gather
__global__ __launch_bounds__(256)
void grescore_kernel(const float* __restrict__ gmax,
                     const float* __restrict__ th,
                     const float* __restrict__ qn,
                     const float* __restrict__ inorm,
                     const float* __restrict__ bank,
                     const float* __restrict__ svt,
                     float* __restrict__ out) {
    __shared__ float qns[D_DIM];
    __shared__ int glist[CAPG];
    __shared__ unsigned long long keys2[CAPG * K16];   // 48 KB
    __shared__ unsigned long long wred[4];
    __shared__ int winI[K16];
    __shared__ int gcntS;
    int b = blockIdx.x, t = threadIdx.x;
    int w = t >> 6, l = t & 63;

    qns[t] = qn[(size_t)b * D_DIM + t];
    if (t == 0) gcntS = 0;
    __syncthreads();
    float thb = th[b];
    for (int g = t; g < NGRP; g += 256) {
        if (gmax[(size_t)b * GSTRIDE + g] >= thb) {
            int p = atomicAdd(&gcntS, 1);
            if (p < CAPG) glist[p] = g;
        }
    }
    __syncthreads();
    int ng = gcntS < CAPG ? gcntS : CAPG;
    int ncand = ng * K16;

    const float4* bank4 = reinterpret_cast<const float4*>(bank);
    float4 qv = reinterpret_cast<const float4*>(qns)[l];
    // 2-way software pipeline: two 1KB candidate rows in flight per wave
    for (int ci = w; ci < ncand; ci += 8) {
        int jA = glist[ci >> 4] * K16 + (ci & 15);
        int ci2 = ci + 4;
        bool has2 = ci2 < ncand;
        int jB = has2 ? (glist[ci2 >> 4] * K16 + (ci2 & 15)) : jA;
        float4 bvA = bank4[(size_t)jA * 64 + l];
        float4 bvB = bank4[(size_t)jB * 64 + l];
        float dA = qv.x * bvA.x + qv.y * bvA.y + qv.z * bvA.z + qv.w * bvA.w;
        float dB = qv.x * bvB.x + qv.y * bvB.y + qv.z * bvB.z + qv.w * bvB.w;
#pragma unroll
        for (int off = 32; off > 0; off >>= 1) dA += __shfl_down(dA, off, 64);
#pragma unroll
        for (int off = 32; off > 0; off >>= 1) dB += __shfl_down(dB, off, 64);
        if (l == 0) {
            float sA = 0.5f * (dA * inorm[jA]) + 0.5f * svt[(size_t)b * N_BANK + jA];
            keys2[ci] = pack_key(sA, jA);
            if (has2) {
                float sB = 0.5f * (dB * inorm[jB]) + 0.5f * svt[(size_t)b * N_BANK + jB];
                keys2[ci2] = pack_key(sB, jB);
            }
        }
    }
    __syncthreads();

    for (int r = 0; r < K16; ++r) {
        unsigned long long best = 0ull;
        for (int i2 = t; i2 < ncand; i2 += 256) best = umax64(best, keys2[i2]);
#pragma unroll
        for (int off = 32; off > 0; off >>= 1) best = umax64(best, shfl_down_u64(best, off));
        if (l == 0) wred[w] = best;
        __syncthreads();
        unsigned long long W = umax64(umax64(wred[0], wred[1]), umax64(wred[2], wred[3]));
        if (t == 0) winI[r] = key_idx(W);
        for (int i2 = t; i2 < ncand; i2 += 256)
            if (keys2[i2] == W) keys2[i2] = 0ull;
        __syncthreads();
    }

    if (t < K16)
        out[(size_t)B_Q * K16 * D_DIM + (size_t)b * K16 + t] = (float)winI[t];
    float4* out4 = reinterpret_cast<float4*>(out);
    for (int u = t; u < K16 * 64; u += 256) {
        int r = u >> 6, cc = u & 63;
        out4[((size_t)b * K16 + r) * 64 + cc] = bank4[(size_t)winI[r] * 64 + cc];
    }
}

// ================= FALLBACK (verified round-1) PATH =================
#define FBT 64
#define FJT 64
#define FKC 64
#define FNS 128
#define FNC ((N_BANK + FJT - 1) / FJT)

__global__ void inorm_kernel(const float* __restrict__ bank,
                             float* __restrict__ inorm) {
    int w = threadIdx.x >> 6;
    int lane = threadIdx.x & 63;
    int j = blockIdx.x * 4 + w;
    if (j >= N_BANK) return;
    const float4* r4 = reinterpret_cast<const float4*>(bank + (size_t)j * D_DIM);
    float4 v = r4[lane];
    float ss = v.x * v.x + v.y * v.y + v.z * v.z + v.w * v.w;
#pragma unroll
    for (int off = 32; off > 0; off >>= 1) ss += __shfl_down(ss, off, 64);
    if (lane == 0) inorm[j] = 1.0f / fmaxf(sqrtf(ss), 1e-12f);
}

__global__ void fb_qn_kernel(const float* __restrict__ z_ego,
                             const float* __restrict__ W,
                             float* __restrict__ qn) {
    __shared__ float zs[D_DIM];
    __shared__ float red[4];
    int b = blockIdx.x;
    int t = threadIdx.x;
    zs[t] = z_ego[b * D_DIM + t];
    __syncthreads();
    const float4* W4 = reinterpret_cast<const float4*>(W + (size_t)t * D_DIM);
    float acc = 0.f;
#pragma unroll 8
    for (int u = 0; u < 64; ++u) {
        float4 w = W4[u];
        acc += w.x * zs[u * 4 + 0]; acc += w.y * zs[u * 4 + 1];
        acc += w.z * zs[u * 4 + 2]; acc += w.w * zs[u * 4 + 3];
    }
    float ss = acc * acc;
#pragma unroll
    for (int off = 32; off > 0; off >>= 1) ss += __shfl_down(ss, off, 64);
    if ((t & 63) == 0) red[t >> 6] = ss;
    __syncthreads();
    float tot = red[0] + red[1] + red[2] + red[3];
    qn[b * D_DIM + t] = acc / fmaxf(sqrtf(tot), 1e-12f);
}

__global__ __launch_bounds__(256)
void fb_score_topk_kernel(const float* __restrict__ qn,
                          const float* __restrict__ bank,
                          const float* __restrict__ svt,
                          const float* __restrict__ inorm,
                          float* __restrict__ psc,
                          int* __restrict__ pid) {
    __shared__ float As[FKC][FBT];
    __shared__ float Bsh[FKC][FJT];
    __shared__ float Ss[FBT][FJT + 1];
    int slice = blockIdx.x;
    int qbase = blockIdx.y * FBT;
    int t = threadIdx.x;
    int tq = t >> 4, tj = t & 15;
    int q0 = tq * 4, j0l = tj * 4;
    float sc[K16]; int id[K16];
#pragma unroll
    for (int i = 0; i < K16; ++i) { sc[i] = -INFINITY; id[i] = 0x7fffffff; }
    for (int c = slice; c < FNC; c += FNS) {
        int j0 = c * FJT;
        float acc[4][4];
#pragma unroll
        for (int a = 0; a < 4; ++a)
#pragma unroll
            for (int b2 = 0; b2 < 4; ++b2) acc[a][b2] = 0.f;
        for (int kc = 0; kc < D_DIM; kc += FKC) {
            __syncthreads();
#pragma unroll
            for (int r = 0; r < 4; ++r) {
                int idx = t + 256 * r;
                int q = idx & 63, kv = idx >> 6;
                float4 v = *reinterpret_cast<const float4*>(
                    &qn[(size_t)(qbase + q) * D_DIM + kc + kv * 4]);
                As[kv * 4 + 0][q] = v.x; As[kv * 4 + 1][q] = v.y;
                As[kv * 4 + 2][q] = v.z; As[kv * 4 + 3][q] = v.w;
            }
#pragma unroll
            for (int r = 0; r < 4; ++r) {
                int idx = t + 256 * r;
                int j = idx & 63, kv = idx >> 6;
                int jg = j0 + j;
                float4 v = make_float4(0.f, 0.f, 0.f, 0.f);
                if (jg < N_BANK)
                    v = *reinterpret_cast<const float4*>(
                        &bank[(size_t)jg * D_DIM + kc + kv * 4]);
                Bsh[kv * 4 + 0][j] = v.x; Bsh[kv * 4 + 1][j] = v.y;
                Bsh[kv * 4 + 2][j] = v.z; Bsh[kv * 4 + 3][j] = v.w;
            }
            __syncthreads();
#pragma unroll
            for (int k = 0; k < FKC; ++k) {
                float4 av = *reinterpret_cast<const float4*>(&As[k][q0]);
                float4 bv = *reinterpret_cast<const float4*>(&Bsh[k][j0l]);
                float a[4] = {av.x, av.y, av.z, av.w};
                float bb[4] = {bv.x, bv.y, bv.z, bv.w};
#pragma unroll
                for (int qi = 0; qi < 4; ++qi)
#pragma unroll
                    for (int ji = 0; ji < 4; ++ji) acc[qi][ji] += a[qi] * bb[ji];
            }
        }
        bool full = (j0 + FJT <= N_BANK);
        if (full) {
            float4 inv = *reinterpret_cast<const float4*>(&inorm[j0 + j0l]);
            float iv[4] = {inv.x, inv.y, inv.z, inv.w};
#pragma unroll
            for (int qi = 0; qi < 4; ++qi) {
                int q = qbase + q0 + qi;
                float4 svv = *reinterpret_cast<const float4*>(
                    &svt[(size_t)q * N_BANK + j0 + j0l]);
                float s[4] = {svv.x, svv.y, svv.z, svv.w};
#pragma unroll
                for (int ji = 0; ji < 4; ++ji)
                    Ss[q0 + qi][j0l + ji] = 0.5f * (acc[qi][ji] * iv[ji]) + 0.5f * s[ji];
            }
        } else {
#pragma unroll
            for (int qi = 0; qi < 4; ++qi) {
                int q = qbase + q0 + qi;
#pragma unroll
                for (int ji = 0; ji < 4; ++ji) {
                    int jg = j0 + j0l + ji;
                    float s = -INFINITY;
                    if (jg < N_BANK)
                        s = 0.5f * (acc[qi][ji] * inorm[jg]) + 0.5f * svt[(size_t)q * N_BANK + jg];
                    Ss[q0 + qi][j0l + ji] = s;
                }
            }
        }
        __syncthreads();
        if (t < FBT) {
#pragma unroll 1
            for (int jj = 0; jj < FJT; ++jj) {
                int jg = j0 + jj;
                if (jg >= N_BANK) break;
                float s = Ss[t][jj];
                if (s > sc[K16 - 1] || (s == sc[K16 - 1] && jg < id[K16 - 1])) {
                    float cs = s; int ci = jg;
#pragma unroll
                    for (int i = 0; i < K16; ++i) {
                        bool bt2 = (cs > sc[i]) || (cs == sc[i] && ci < id[i]);
                        float ts = sc[i]; int ti = id[i];
                        if (bt2) { sc[i] = cs; id[i] = ci; cs = ts; ci = ti; }
                    }
                }
            }
        }
    }
    if (t < FBT) {
        int q = qbase + t;
        size_t base = ((size_t)q * FNS + slice) * K16;
#pragma unroll
        for (int i = 0; i < K16; ++i) { psc[base + i] = sc[i]; pid[base + i] = id[i]; }
    }
}

__global__ __launch_bounds__(256)
void fb_merge_kernel(const float* __restrict__ psc,
                     const int* __restrict__ pid,
                     const float* __restrict__ bank,
                     float* __restrict__ out) {
    __shared__ unsigned long long keys[FNS * K16];
    __shared__ unsigned long long wred[4];
    __shared__ int win[K16];
    int b = blockIdx.x, t = threadIdx.x;
    for (int i = t; i < FNS * K16; i += 256) {
        float s = psc[(size_t)b * FNS * K16 + i];
        unsigned int u = __float_as_uint(s);
        u ^= (u & 0x80000000u) ? 0xFFFFFFFFu : 0x80000000u;
        unsigned int iv = ~(unsigned int)pid[(size_t)b * FNS * K16 + i];
        keys[i] = ((unsigned long long)u << 32) | iv;
    }
    __syncthreads();
    for (int r = 0; r < K16; ++r) {
        unsigned long long best = 0ull;
        for (int i = t; i < FNS * K16; i += 256) best = umax64(best, keys[i]);
#pragma unroll
        for (int off = 32; off > 0; off >>= 1) best = umax64(best, shfl_down_u64(best, off));
        if ((t & 63) == 0) wred[t >> 6] = best;
        __syncthreads();
        unsigned long long w = umax64(umax64(wred[0], wred[1]), umax64(wred[2], wred[3]));
        if (t == 0) win[r] = (int)(~(unsigned int)w);
        for (int i = t; i < FNS * K16; i += 256)
            if (keys[i] == w) keys[i] = 0ull;
        __syncthreads();
    }
    if (t < K16)
        out[(size_t)B_Q * K16 * D_DIM + (size_t)b * K16 + t] = (float)win[t];
    const float4* bank4 = reinterpret_cast<const float4*>(bank);
    float4* out4 = reinterpret_cast<float4*>(out);
    for (int u = t; u < K16 * 64; u += 256) {
        int r = u >> 6, c = u & 63;
        out4[((size_t)b * K16 + r) * 64 + c] = bank4[(size_t)win[r] * 64 + c];
    }
}

// ---------------- launcher ----------------
extern "C" void kernel_launch(void* const* d_in, const int* in_sizes, int n_in,
                              void* d_out, int out_size, void* d_ws, size_t ws_size,
                              hipStream_t stream) {
    const float* z_ego = (const float*)d_in[0];
    const float* bank  = (const float*)d_in[1];
    const float* svt   = (const float*)d_in[2];
    const float* W     = (const float*)d_in[3];
    float* out = (float*)d_out;
    char* ws = (char*)d_ws;

    if (ws_size >= WS_NEED) {
        float* qn             = (float*)(ws + OFF_QN);
        unsigned short* qnt   = (unsigned short*)(ws + OFF_QNT);
        float* inorm          = (float*)(ws + OFF_INORM);
        float* th             = (float*)(ws + OFF_TH);
        float* gmax           = (float*)(ws + OFF_GMAX);
        unsigned short* bankt = (unsigned short*)(ws + OFF_BANKT);

        qn_prep_kernel<<<B_Q, 256, 0, stream>>>(z_ego, W, qn, qnt);
        prep_bank_kernel<<<NCHUNK, 256, 0, stream>>>(bank, inorm, bankt);
        screen4_kernel<<<NSL2 * 4, 256, 0, stream>>>(qnt, bankt, svt, gmax);
        gthresh_kernel<<<B_Q, 256, 0, stream>>>(gmax, th);
        grescore_kernel<<<B_Q, 256, 0, stream>>>(gmax, th, qn, inorm, bank, svt, out);
    } else {
        float* qn    = (float*)(ws + 0);
        float* inorm = (float*)(ws + FB_OFF_INORM);
        float* psc   = (float*)(ws + FB_OFF_PSC);
        int*   pid   = (int*)(ws + FB_OFF_PID);
        fb_qn_kernel<<<B_Q, 256, 0, stream>>>(z_ego, W, qn);
        inorm_kernel<<<(N_BANK + 3) / 4, 256, 0, stream>>>(bank, inorm);
        dim3 grid(FNS, B_Q / FBT);
        fb_score_topk_kernel<<<grid, 256, 0, stream>>>(qn, bank, svt, inorm, psc, pid);
        fb_merge_kernel<<<B_Q, 256, 0, stream>>>(psc, pid, bank, out);
    }
}

// Round 4
// 677.522 us; speedup vs baseline: 1.0802x; 1.0313x over previous
//
#include <hip/hip_runtime.h>
#include <math.h>
#include <stdint.h>

#define B_Q    512
#define N_BANK 100000
#define D_DIM  256
#define K16    16

// ---------------- MFMA path constants ----------------
#define NSL2   256                          // j-slices for screen (grid = NSL2*4)
#define NCHUNK 1563                         // ceil(100000/64)
#define TROW   264                          // bf16 elems per padded row (256 + 8 pad)
#define CHUNK_USHORT (64 * TROW)            // 16896
#define CHUNK_BYTES  (CHUNK_USHORT * 2)     // 33792
#define NGRP   6250                         // 100000 / 16 j-groups per query
#define GSTRIDE 6272                        // padded group row stride (floats)
#define MARGIN 5e-3f                        // >= 2*eps_screen (worst-case bf16 dot bound)
#define CAPG   384                          // max surviving groups per query (exp ~30)

#define SLAB_FLOATS 32768                   // 512 q * 64 j per chunk slab (fp32)

// ws layout (bytes)
#define OFF_QN     0                        // fp32 qn: 512KB
#define OFF_QNT    0x80000                  // bf16 tiled qn: 270336
#define OFF_INORM  0x100000                 // fp32 inorm: 400000
#define OFF_TH     0x170000                 // fp32 th[512]
#define OFF_GMAX   0x400000                 // fp32 gmax[512][6272] = 12.85MB (ends < 0x1400000)
#define OFF_BANKT  0x1400000                // bf16 tiled bank: 1563*33792 (ends 0x465F800)
#define WS_NEED    ((size_t)OFF_BANKT + (size_t)NCHUNK * CHUNK_BYTES)
#define OFF_SVTT   0x4800000                // fp32 chunk-major svt: 1563*131072 = 204.9MB
#define WS_NEED2   ((size_t)OFF_SVTT + (size_t)NCHUNK * SLAB_FLOATS * 4)

// fallback path ws layout
#define FB_OFF_INORM (B_Q * D_DIM * 4)
#define FB_OFF_PSC   (1024 * 1024)
#define FB_OFF_PID   (FB_OFF_PSC + B_Q * 128 * K16 * 4)

typedef __attribute__((ext_vector_type(8))) short short8;
typedef __attribute__((ext_vector_type(4))) float floatx4;

typedef __attribute__((address_space(1))) const unsigned char gu8_t;
typedef __attribute__((address_space(3))) unsigned char lu8_t;

// ---------------- helpers ----------------
__device__ inline unsigned short f2bf(float x) {   // RNE fp32 -> bf16
    unsigned int u = __float_as_uint(x);
    unsigned int r = (u + 0x7FFFu + ((u >> 16) & 1u)) >> 16;
    return (unsigned short)r;
}
__device__ inline unsigned long long pack_key(float s, int idx) {
    unsigned int u = __float_as_uint(s);
    u ^= (u & 0x80000000u) ? 0xFFFFFFFFu : 0x80000000u;  // order-preserving
    return ((unsigned long long)u << 32) | (unsigned int)(~(unsigned int)idx);
}
__device__ inline int key_idx(unsigned long long k) {
    return (int)(~(unsigned int)(k & 0xFFFFFFFFull));
}
__device__ inline unsigned long long shfl_down_u64(unsigned long long x, int off) {
    unsigned int lo = (unsigned int)x;
    unsigned int hi = (unsigned int)(x >> 32);
    lo = __shfl_down(lo, off, 64);
    hi = __shfl_down(hi, off, 64);
    return ((unsigned long long)hi << 32) | lo;
}
__device__ inline unsigned long long umax64(unsigned long long a, unsigned long long b) {
    return a > b ? a : b;
}

// ================= MFMA PATH =================

// qn = normalize(z_ego @ W^T) fp32, plus bf16 padded-tiled copy
__global__ void qn_prep_kernel(const float* __restrict__ z_ego,
                               const float* __restrict__ W,
                               float* __restrict__ qn,
                               unsigned short* __restrict__ qnt) {
    __shared__ float zs[D_DIM];
    __shared__ float red[4];
    int b = blockIdx.x;
    int t = threadIdx.x;
    zs[t] = z_ego[b * D_DIM + t];
    __syncthreads();
    const float4* W4 = reinterpret_cast<const float4*>(W + (size_t)t * D_DIM);
    float acc = 0.f;
#pragma unroll 8
    for (int u = 0; u < 64; ++u) {
        float4 w = W4[u];
        acc += w.x * zs[u * 4 + 0];
        acc += w.y * zs[u * 4 + 1];
        acc += w.z * zs[u * 4 + 2];
        acc += w.w * zs[u * 4 + 3];
    }
    float ss = acc * acc;
#pragma unroll
    for (int off = 32; off > 0; off >>= 1) ss += __shfl_down(ss, off, 64);
    if ((t & 63) == 0) red[t >> 6] = ss;
    __syncthreads();
    float tot = red[0] + red[1] + red[2] + red[3];
    float n = fmaxf(sqrtf(tot), 1e-12f);
    float v = acc / n;
    qn[b * D_DIM + t] = v;
    qnt[(size_t)(b >> 6) * CHUNK_USHORT + (size_t)(b & 63) * TROW + t] = f2bf(v);
}

// fused: row norms + bf16 normalized tiled bank
__global__ __launch_bounds__(256)
void prep_bank_kernel(const float* __restrict__ bank,
                      float* __restrict__ inorm,
                      unsigned short* __restrict__ bankt) {
    int c = blockIdx.x;
    int t = threadIdx.x, w = t >> 6, l = t & 63;
    unsigned short* dst = bankt + (size_t)c * CHUNK_USHORT;
#pragma unroll 1
    for (int rr = 0; rr < 16; ++rr) {
        int row = w * 16 + rr;
        int jg = c * 64 + row;
        ushort4 o = {0, 0, 0, 0};
        if (jg < N_BANK) {
            float4 v = *reinterpret_cast<const float4*>(bank + (size_t)jg * D_DIM + l * 4);
            float ss = v.x * v.x + v.y * v.y + v.z * v.z + v.w * v.w;
#pragma unroll
            for (int off = 1; off < 64; off <<= 1) ss += __shfl_xor(ss, off, 64);
            float inv = 1.0f / fmaxf(sqrtf(ss), 1e-12f);
            o.x = f2bf(v.x * inv); o.y = f2bf(v.y * inv);
            o.z = f2bf(v.z * inv); o.w = f2bf(v.w * inv);
            if (l == 0) inorm[jg] = inv;
        }
        *reinterpret_cast<ushort4*>(dst + (size_t)row * TROW + l * 4) = o;
    }
}

// svt tiled transpose: [q][j] -> svtt[c][q][64 j'], fp32 (bit-identical values).
// Tile = 8 q x 1024 j (16 chunks). Reads: 8 x 4KB contiguous rows (page-friendly).
// Writes: per chunk, 8 consecutive q rows = 2KB contiguous in the slab.
#define RT_Q 8
#define RT_J 1024
__global__ __launch_bounds__(256)
void svt_repack_kernel(const float* __restrict__ svt,
                       float* __restrict__ svtt) {
    __shared__ float tile[RT_Q][RT_J + 4];
    int t = threadIdx.x;
    int jt = blockIdx.x;                 // j-tile (0..97)
    int q0 = blockIdx.y * RT_Q;          // 0..504
    int jl = t * 4;                      // 0..1020
#pragma unroll
    for (int qq = 0; qq < RT_Q; ++qq) {
        int j = jt * RT_J + jl;
        float4 v = make_float4(0.f, 0.f, 0.f, 0.f);
        if (j < N_BANK)                  // N_BANK % 4 == 0 -> full float4 valid
            v = *reinterpret_cast<const float4*>(svt + (size_t)(q0 + qq) * N_BANK + j);
        *reinterpret_cast<float4*>(&tile[qq][jl]) = v;
    }
    __syncthreads();
    int half = t >> 7;                   // 2 chunks per pass
    int q1 = (t >> 4) & 7;
    int m = t & 15;
#pragma unroll
    for (int p = 0; p < 8; ++p) {
        int cc = p * 2 + half;
        int c = jt * 16 + cc;
        if (c < NCHUNK) {
            float4 v = *reinterpret_cast<const float4*>(&tile[q1][cc * 64 + m * 4]);
            *reinterpret_cast<float4*>(svtt + (size_t)c * SLAB_FLOATS
                                       + (size_t)(q0 + q1) * 64 + m * 4) = v;
        }
    }
}

// screen5: identical arithmetic to screen4, but svt read from the chunk-major
// repacked slab (contiguous 128KB per chunk, shared by the slice's 4 co-XCD
// blocks) -> DRAM page-efficient streaming instead of 256B scattered touches.
__global__ __launch_bounds__(256, 4)
void screen5_kernel(const unsigned short* __restrict__ qnt,
                    const unsigned short* __restrict__ bankt,
                    const float* __restrict__ svtt,
                    float* __restrict__ gmax) {
    __shared__ unsigned short lbank[CHUNK_USHORT];   // 33792 B
    int t = threadIdx.x, w = t >> 6, l = t & 63;
    int lane16 = l & 15, quad = l >> 4;

    // bid -> (slice, qb): XCD (bid&7) owns slices [32*xcd, 32*xcd+31];
    // the 4 q-blocks of one slice are consecutive bids on the same XCD.
    int bid = blockIdx.x;
    int xcd = bid & 7;
    int i = bid >> 3;                    // 0..127
    int slice = (xcd << 5) + (i >> 2);   // 0..255
    int qb = i & 3;                      // q-block 0..3 (128 queries each)

    int qt = qb * 4 + w;                 // this wave's 32-query tile (0..15)
    int qbase = qt * 32;

    // A-fragments (32 queries x 256 k) -> AGPR-resident
    short8 afrag[2][8];
    {
        const unsigned short* abase = qnt + (size_t)(qt >> 1) * CHUNK_USHORT
                                          + (size_t)((qt & 1) * 32) * TROW;
#pragma unroll
        for (int s = 0; s < 2; ++s)
#pragma unroll
            for (int k = 0; k < 8; ++k)
                afrag[s][k] = *reinterpret_cast<const short8*>(
                    abase + (size_t)(16 * s + lane16) * TROW + k * 32 + quad * 8);
    }

    // per-(s,r) base pointer into the repacked slabs for this lane
    const float* sp[2][4];
#pragma unroll
    for (int s = 0; s < 2; ++s)
#pragma unroll
        for (int r = 0; r < 4; ++r)
            sp[s][r] = svtt + (size_t)(qbase + 16 * s + 4 * quad + r) * 64 + lane16;

    for (int c = slice; c < NCHUNK; c += NSL2) {
        int j0 = c * 64;

        // ---- stage chunk into LDS (dense, async). Each wave covers 1KB per call.
        {
            const unsigned char* gsrc = (const unsigned char*)bankt + (size_t)c * CHUNK_BYTES;
            unsigned char* lbase = (unsigned char*)lbank;
#pragma unroll
            for (int i2 = 0; i2 < 8; ++i2) {
                int off = i2 * 4096 + w * 1024;
                __builtin_amdgcn_global_load_lds((gu8_t*)(gsrc + off + l * 16),
                                                 (lu8_t*)(lbase + off), 16, 0, 0);
            }
            int off8 = 32768 + w * 256;  // tail 1024B, 4B per lane
            __builtin_amdgcn_global_load_lds((gu8_t*)(gsrc + off8 + l * 4),
                                             (lu8_t*)(lbase + off8), 4, 0, 0);
        }

        // ---- batched svt loads from the chunk slab (contiguous, pad zero-filled)
        float sv[4][2][4];
        {
            size_t slabOff = (size_t)c * SLAB_FLOATS;
#pragma unroll
            for (int s = 0; s < 2; ++s)
#pragma unroll
                for (int r = 0; r < 4; ++r) {
                    const float* rp = sp[s][r] + slabOff;
#pragma unroll
                    for (int jg = 0; jg < 4; ++jg)
                        sv[jg][s][r] = rp[16 * jg];
                }
        }

        __syncthreads();   // staging + svt complete

        int g0 = c * 4;
#pragma unroll
        for (int jg = 0; jg < 4; ++jg) {
            floatx4 acc0 = (floatx4){0.f, 0.f, 0.f, 0.f};
            floatx4 acc1 = (floatx4){0.f, 0.f, 0.f, 0.f};
            const unsigned short* bbase = lbank + (size_t)(16 * jg + lane16) * TROW + quad * 8;
#pragma unroll
            for (int k = 0; k < 8; ++k) {
                short8 bfrag = *reinterpret_cast<const short8*>(bbase + k * 32);
                acc0 = __builtin_amdgcn_mfma_f32_16x16x32_bf16(afrag[0][k], bfrag, acc0, 0, 0, 0);
                acc1 = __builtin_amdgcn_mfma_f32_16x16x32_bf16(afrag[1][k], bfrag, acc1, 0, 0, 0);
            }

            int jglob = j0 + 16 * jg + lane16;
            bool inb = jglob < N_BANK;
            int g = g0 + jg;
            bool doStore = (lane16 == 0) && (g < NGRP);
#pragma unroll
            for (int s = 0; s < 2; ++s) {
#pragma unroll
                for (int r = 0; r < 4; ++r) {
                    float a = (s == 0) ? acc0[r] : acc1[r];
                    float score = inb ? (0.5f * a + 0.5f * sv[jg][s][r]) : -INFINITY;
                    // max over the 16 j's (lane16 bits 0..3)
                    score = fmaxf(score, __shfl_xor(score, 1, 64));
                    score = fmaxf(score, __shfl_xor(score, 2, 64));
                    score = fmaxf(score, __shfl_xor(score, 4, 64));
                    score = fmaxf(score, __shfl_xor(score, 8, 64));
                    if (doStore) {
                        int q = qbase + 16 * s + 4 * quad + r;
                        gmax[(size_t)q * GSTRIDE + g] = score;
                    }
                }
            }
        }
        __syncthreads();   // protect lbank before next chunk's staging
    }
}

// screen4 (tier-2, kept verbatim): direct scattered svt reads
__global__ __launch_bounds__(256, 4)
void screen4_kernel(const unsigned short* __restrict__ qnt,
                    const unsigned short* __restrict__ bankt,
                    const float* __restrict__ svt,
                    float* __restrict__ gmax) {
    __shared__ unsigned short lbank[CHUNK_USHORT];   // 33792 B
    int t = threadIdx.x, w = t >> 6, l = t & 63;
    int lane16 = l & 15, quad = l >> 4;

    int bid = blockIdx.x;
    int xcd = bid & 7;
    int i = bid >> 3;
    int slice = (xcd << 5) + (i >> 2);
    int qb = i & 3;

    int qt = qb * 4 + w;
    int qbase = qt * 32;

    short8 afrag[2][8];
    {
        const unsigned short* abase = qnt + (size_t)(qt >> 1) * CHUNK_USHORT
                                          + (size_t)((qt & 1) * 32) * TROW;
#pragma unroll
        for (int s = 0; s < 2; ++s)
#pragma unroll
            for (int k = 0; k < 8; ++k)
                afrag[s][k] = *reinterpret_cast<const short8*>(
                    abase + (size_t)(16 * s + lane16) * TROW + k * 32 + quad * 8);
    }

    const float* svr[2][4];
#pragma unroll
    for (int s = 0; s < 2; ++s)
#pragma unroll
        for (int r = 0; r < 4; ++r)
            svr[s][r] = svt + (size_t)(qbase + 16 * s + 4 * quad + r) * (size_t)N_BANK;

    for (int c = slice; c < NCHUNK; c += NSL2) {
        int j0 = c * 64;
        {
            const unsigned char* gsrc = (const unsigned char*)bankt + (size_t)c * CHUNK_BYTES;
            unsigned char* lbase = (unsigned char*)lbank;
#pragma unroll
            for (int i2 = 0; i2 < 8; ++i2) {
                int off = i2 * 4096 + w * 1024;
                __builtin_amdgcn_global_load_lds((gu8_t*)(gsrc + off + l * 16),
                                                 (lu8_t*)(lbase + off), 16, 0, 0);
            }
            int off8 = 32768 + w * 256;
            __builtin_amdgcn_global_load_lds((gu8_t*)(gsrc + off8 + l * 4),
                                             (lu8_t*)(lbase + off8), 4, 0, 0);
        }

        float sv[4][2][4];
#pragma unroll
        for (int s = 0; s < 2; ++s)
#pragma unroll
            for (int r = 0; r < 4; ++r) {
                const float* rp = svr[s][r] + j0 + lane16;
#pragma unroll
                for (int jg = 0; jg < 4; ++jg) {
                    int jglob = j0 + 16 * jg + lane16;
                    sv[jg][s][r] = (jglob < N_BANK) ? rp[16 * jg] : 0.f;
                }
            }

        __syncthreads();

        int g0 = c * 4;
#pragma unroll
        for (int jg = 0; jg < 4; ++jg) {
            floatx4 acc0 = (floatx4){0.f, 0.f, 0.f, 0.f};
            floatx4 acc1 = (floatx4){0.f, 0.f, 0.f, 0.f};
            const unsigned short* bbase = lbank + (size_t)(16 * jg + lane16) * TROW + quad * 8;
#pragma unroll
            for (int k = 0; k < 8; ++k) {
                short8 bfrag = *reinterpret_cast<const short8*>(bbase + k * 32);
                acc0 = __builtin_amdgcn_mfma_f32_16x16x32_bf16(afrag[0][k], bfrag, acc0, 0, 0, 0);
                acc1 = __builtin_amdgcn_mfma_f32_16x16x32_bf16(afrag[1][k], bfrag, acc1, 0, 0, 0);
            }

            int jglob = j0 + 16 * jg + lane16;
            bool inb = jglob < N_BANK;
            int g = g0 + jg;
            bool doStore = (lane16 == 0) && (g < NGRP);
#pragma unroll
            for (int s = 0; s < 2; ++s) {
#pragma unroll
                for (int r = 0; r < 4; ++r) {
                    float a = (s == 0) ? acc0[r] : acc1[r];
                    float score = inb ? (0.5f * a + 0.5f * sv[jg][s][r]) : -INFINITY;
                    score = fmaxf(score, __shfl_xor(score, 1, 64));
                    score = fmaxf(score, __shfl_xor(score, 2, 64));
                    score = fmaxf(score, __shfl_xor(score, 4, 64));
                    score = fmaxf(score, __shfl_xor(score, 8, 64));
                    if (doStore) {
                        int q = qbase + 16 * s + 4 * quad + r;
                        gmax[(size_t)q * GSTRIDE + g] = score;
                    }
                }
            }
        }
        __syncthreads();
    }
}

// per-query: 16th-largest group-max - margin -> th
__global__ __launch_bounds__(256)
void gthresh_kernel(const float* __restrict__ gmax,
                    float* __restrict__ th) {
    __shared__ float buf[NGRP];    // 25 KB
    __shared__ float red[4];
    int q = blockIdx.x, t = threadIdx.x, w = t >> 6;
    for (int i = t; i < NGRP; i += 256) buf[i] = gmax[(size_t)q * GSTRIDE + i];
    __syncthreads();
    float s16 = -INFINITY;
    for (int r = 0; r < K16; ++r) {
        float m = -INFINITY;
        for (int i = t; i < NGRP; i += 256) m = fmaxf(m, buf[i]);
#pragma unroll
        for (int off = 32; off > 0; off >>= 1) m = fmaxf(m, __shfl_down(m, off, 64));
        if ((t & 63) == 0) red[w] = m;
        __syncthreads();
        m = fmaxf(fmaxf(red[0], red[1]), fmaxf(red[2], red[3]));
        if (r == K16 - 1) s16 = m;
        if (r < K16 - 1) {
            for (int i = t; i < NGRP; i += 256)
                if (buf[i] == m) buf[i] = -INFINITY;
        }
        __syncthreads();
    }
    if (t == 0) th[q] = s16 - MARGIN;
}

// per-query: collect groups >= th, exact fp32 rescore of members, top-16, gather
__global__ __launch_bounds__(256)
void grescore_kernel(const float* __restrict__ gmax,
                     const float* __restrict__ th,
                     const float* __restrict__ qn,
                     const float* __restrict__ inorm,
                     const float* __restrict__ bank,
                     const float* __restrict__ svt,
                     float* __restrict__ out) {
    __shared__ float qns[D_DIM];
    __shared__ int glist[CAPG];
    __shared__ unsigned long long keys2[CAPG * K16];   // 48 KB
    __shared__ unsigned long long wred[4];
    __shared__ int winI[K16];
    __shared__ int gcntS;
    int b = blockIdx.x, t = threadIdx.x;
    int w = t >> 6, l = t & 63;

    qns[t] = qn[(size_t)b * D_DIM + t];
    if (t == 0) gcntS = 0;
    __syncthreads();
    float thb = th[b];
    for (int g = t; g < NGRP; g += 256) {
        if (gmax[(size_t)b * GSTRIDE + g] >= thb) {
            int p = atomicAdd(&gcntS, 1);
            if (p < CAPG) glist[p] = g;
        }
    }
    __syncthreads();
    int ng = gcntS < CAPG ? gcntS : CAPG;
    int ncand = ng * K16;

    const float4* bank4 = reinterpret_cast<const float4*>(bank);
    float4 qv = reinterpret_cast<const float4*>(qns)[l];
    // 2-way software pipeline: two 1KB candidate rows in flight per wave
    for (int ci = w; ci < ncand; ci += 8) {
        int jA = glist[ci >> 4] * K16 + (ci & 15);
        int ci2 = ci + 4;
        bool has2 = ci2 < ncand;
        int jB = has2 ? (glist[ci2 >> 4] * K16 + (ci2 & 15)) : jA;
        float4 bvA = bank4[(size_t)jA * 64 + l];
        float4 bvB = bank4[(size_t)jB * 64 + l];
        float dA = qv.x * bvA.x + qv.y * bvA.y + qv.z * bvA.z + qv.w * bvA.w;
        float dB = qv.x * bvB.x + qv.y * bvB.y + qv.z * bvB.z + qv.w * bvB.w;
#pragma unroll
        for (int off = 32; off > 0; off >>= 1) dA += __shfl_down(dA, off, 64);
#pragma unroll
        for (int off = 32; off > 0; off >>= 1) dB += __shfl_down(dB, off, 64);
        if (l == 0) {
            float sA = 0.5f * (dA * inorm[jA]) + 0.5f * svt[(size_t)b * N_BANK + jA];
            keys2[ci] = pack_key(sA, jA);
            if (has2) {
                float sB = 0.5f * (dB * inorm[jB]) + 0.5f * svt[(size_t)b * N_BANK + jB];
                keys2[ci2] = pack_key(sB, jB);
            }
        }
    }
    __syncthreads();

    for (int r = 0; r < K16; ++r) {
        unsigned long long best = 0ull;
        for (int i2 = t; i2 < ncand; i2 += 256) best = umax64(best, keys2[i2]);
#pragma unroll
        for (int off = 32; off > 0; off >>= 1) best = umax64(best, shfl_down_u64(best, off));
        if (l == 0) wred[w] = best;
        __syncthreads();
        unsigned long long W = umax64(umax64(wred[0], wred[1]), umax64(wred[2], wred[3]));
        if (t == 0) winI[r] = key_idx(W);
        for (int i2 = t; i2 < ncand; i2 += 256)
            if (keys2[i2] == W) keys2[i2] = 0ull;
        __syncthreads();
    }

    if (t < K16)
        out[(size_t)B_Q * K16 * D_DIM + (size_t)b * K16 + t] = (float)winI[t];
    float4* out4 = reinterpret_cast<float4*>(out);
    for (int u = t; u < K16 * 64; u += 256) {
        int r = u >> 6, cc = u & 63;
        out4[((size_t)b * K16 + r) * 64 + cc] = bank4[(size_t)winI[r] * 64 + cc];
    }
}

// ================= FALLBACK (verified round-1) PATH =================
#define FBT 64
#define FJT 64
#define FKC 64
#define FNS 128
#define FNC ((N_BANK + FJT - 1) / FJT)

__global__ void inorm_kernel(const float* __restrict__ bank,
                             float* __restrict__ inorm) {
    int w = threadIdx.x >> 6;
    int lane = threadIdx.x & 63;
    int j = blockIdx.x * 4 + w;
    if (j >= N_BANK) return;
    const float4* r4 = reinterpret_cast<const float4*>(bank + (size_t)j * D_DIM);
    float4 v = r4[lane];
    float ss = v.x * v.x + v.y * v.y + v.z * v.z + v.w * v.w;
#pragma unroll
    for (int off = 32; off > 0; off >>= 1) ss += __shfl_down(ss, off, 64);
    if (lane == 0) inorm[j] = 1.0f / fmaxf(sqrtf(ss), 1e-12f);
}

__global__ void fb_qn_kernel(const float* __restrict__ z_ego,
                             const float* __restrict__ W,
                             float* __restrict__ qn) {
    __shared__ float zs[D_DIM];
    __shared__ float red[4];
    int b = blockIdx.x;
    int t = threadIdx.x;
    zs[t] = z_ego[b * D_DIM + t];
    __syncthreads();
    const float4* W4 = reinterpret_cast<const float4*>(W + (size_t)t * D_DIM);
    float acc = 0.f;
#pragma unroll 8
    for (int u = 0; u < 64; ++u) {
        float4 w = W4[u];
        acc += w.x * zs[u * 4 + 0]; acc += w.y * zs[u * 4 + 1];
        acc += w.z * zs[u * 4 + 2]; acc += w.w * zs[u * 4 + 3];
    }
    float ss = acc * acc;
#pragma unroll
    for (int off = 32; off > 0; off >>= 1) ss += __shfl_down(ss, off, 64);
    if ((t & 63) == 0) red[t >> 6] = ss;
    __syncthreads();
    float tot = red[0] + red[1] + red[2] + red[3];
    qn[b * D_DIM + t] = acc / fmaxf(sqrtf(tot), 1e-12f);
}

__global__ __launch_bounds__(256)
void fb_score_topk_kernel(const float* __restrict__ qn,
                          const float* __restrict__ bank,
                          const float* __restrict__ svt,
                          const float* __restrict__ inorm,
                          float* __restrict__ psc,
                          int* __restrict__ pid) {
    __shared__ float As[FKC][FBT];
    __shared__ float Bsh[FKC][FJT];
    __shared__ float Ss[FBT][FJT + 1];
    int slice = blockIdx.x;
    int qbase = blockIdx.y * FBT;
    int t = threadIdx.x;
    int tq = t >> 4, tj = t & 15;
    int q0 = tq * 4, j0l = tj * 4;
    float sc[K16]; int id[K16];
#pragma unroll
    for (int i = 0; i < K16; ++i) { sc[i] = -INFINITY; id[i] = 0x7fffffff; }
    for (int c = slice; c < FNC; c += FNS) {
        int j0 = c * FJT;
        float acc[4][4];
#pragma unroll
        for (int a = 0; a < 4; ++a)
#pragma unroll
            for (int b2 = 0; b2 < 4; ++b2) acc[a][b2] = 0.f;
        for (int kc = 0; kc < D_DIM; kc += FKC) {
            __syncthreads();
#pragma unroll
            for (int r = 0; r < 4; ++r) {
                int idx = t + 256 * r;
                int q = idx & 63, kv = idx >> 6;
                float4 v = *reinterpret_cast<const float4*>(
                    &qn[(size_t)(qbase + q) * D_DIM + kc + kv * 4]);
                As[kv * 4 + 0][q] = v.x; As[kv * 4 + 1][q] = v.y;
                As[kv * 4 + 2][q] = v.z; As[kv * 4 + 3][q] = v.w;
            }
#pragma unroll
            for (int r = 0; r < 4; ++r) {
                int idx = t + 256 * r;
                int j = idx & 63, kv = idx >> 6;
                int jg = j0 + j;
                float4 v = make_float4(0.f, 0.f, 0.f, 0.f);
                if (jg < N_BANK)
                    v = *reinterpret_cast<const float4*>(
                        &bank[(size_t)jg * D_DIM + kc + kv * 4]);
                Bsh[kv * 4 + 0][j] = v.x; Bsh[kv * 4 + 1][j] = v.y;
                Bsh[kv * 4 + 2][j] = v.z; Bsh[kv * 4 + 3][j] = v.w;
            }
            __syncthreads();
#pragma unroll
            for (int k = 0; k < FKC; ++k) {
                float4 av = *reinterpret_cast<const float4*>(&As[k][q0]);
                float4 bv = *reinterpret_cast<const float4*>(&Bsh[k][j0l]);
                float a[4] = {av.x, av.y, av.z, av.w};
                float bb[4] = {bv.x, bv.y, bv.z, bv.w};
#pragma unroll
                for (int qi = 0; qi < 4; ++qi)
#pragma unroll
                    for (int ji = 0; ji < 4; ++ji) acc[qi][ji] += a[qi] * bb[ji];
            }
        }
        bool full = (j0 + FJT <= N_BANK);
        if (full) {
            float4 inv = *reinterpret_cast<const float4*>(&inorm[j0 + j0l]);
            float iv[4] = {inv.x, inv.y, inv.z, inv.w};
#pragma unroll
            for (int qi = 0; qi < 4; ++qi) {
                int q = qbase + q0 + qi;
                float4 svv = *reinterpret_cast<const float4*>(
                    &svt[(size_t)q * N_BANK + j0 + j0l]);
                float s[4] = {svv.x, svv.y, svv.z, svv.w};
#pragma unroll
                for (int ji = 0; ji < 4; ++ji)
                    Ss[q0 + qi][j0l + ji] = 0.5f * (acc[qi][ji] * iv[ji]) + 0.5f * s[ji];
            }
        } else {
#pragma unroll
            for (int qi = 0; qi < 4; ++qi) {
                int q = qbase + q0 + qi;
#pragma unroll
                for (int ji = 0; ji < 4; ++ji) {
                    int jg = j0 + j0l + ji;
                    float s = -INFINITY;
                    if (jg < N_BANK)
                        s = 0.5f * (acc[qi][ji] * inorm[jg]) + 0.5f * svt[(size_t)q * N_BANK + jg];
                    Ss[q0 + qi][j0l + ji] = s;
                }
            }
        }
        __syncthreads();
        if (t < FBT) {
#pragma unroll 1
            for (int jj = 0; jj < FJT; ++jj) {
                int jg = j0 + jj;
                if (jg >= N_BANK) break;
                float s = Ss[t][jj];
                if (s > sc[K16 - 1] || (s == sc[K16 - 1] && jg < id[K16 - 1])) {
                    float cs = s; int ci = jg;
#pragma unroll
                    for (int i = 0; i < K16; ++i) {
                        bool bt2 = (cs > sc[i]) || (cs == sc[i] && ci < id[i]);
                        float ts = sc[i]; int ti = id[i];
                        if (bt2) { sc[i] = cs; id[i] = ci; cs = ts; ci = ti; }
                    }
                }
            }
        }
    }
    if (t < FBT) {
        int q = qbase + t;
        size_t base = ((size_t)q * FNS + slice) * K16;
#pragma unroll
        for (int i = 0; i < K16; ++i) { psc[base + i] = sc[i]; pid[base + i] = id[i]; }
    }
}

__global__ __launch_bounds__(256)
void fb_merge_kernel(const float* __restrict__ psc,
                     const int* __restrict__ pid,
                     const float* __restrict__ bank,
                     float* __restrict__ out) {
    __shared__ unsigned long long keys[FNS * K16];
    __shared__ unsigned long long wred[4];
    __shared__ int win[K16];
    int b = blockIdx.x, t = threadIdx.x;
    for (int i = t; i < FNS * K16; i += 256) {
        float s = psc[(size_t)b * FNS * K16 + i];
        unsigned int u = __float_as_uint(s);
        u ^= (u & 0x80000000u) ? 0xFFFFFFFFu : 0x80000000u;
        unsigned int iv = ~(unsigned int)pid[(size_t)b * FNS * K16 + i];
        keys[i] = ((unsigned long long)u << 32) | iv;
    }
    __syncthreads();
    for (int r = 0; r < K16; ++r) {
        unsigned long long best = 0ull;
        for (int i = t; i < FNS * K16; i += 256) best = umax64(best, keys[i]);
#pragma unroll
        for (int off = 32; off > 0; off >>= 1) best = umax64(best, shfl_down_u64(best, off));
        if ((t & 63) == 0) wred[t >> 6] = best;
        __syncthreads();
        unsigned long long w = umax64(umax64(wred[0], wred[1]), umax64(wred[2], wred[3]));
        if (t == 0) win[r] = (int)(~(unsigned int)w);
        for (int i = t; i < FNS * K16; i += 256)
            if (keys[i] == w) keys[i] = 0ull;
        __syncthreads();
    }
    if (t < K16)
        out[(size_t)B_Q * K16 * D_DIM + (size_t)b * K16 + t] = (float)win[t];
    const float4* bank4 = reinterpret_cast<const float4*>(bank);
    float4* out4 = reinterpret_cast<float4*>(out);
    for (int u = t; u < K16 * 64; u += 256) {
        int r = u >> 6, c = u & 63;
        out4[((size_t)b * K16 + r) * 64 + c] = bank4[(size_t)win[r] * 64 + c];
    }
}

// ---------------- launcher ----------------
extern "C" void kernel_launch(void* const* d_in, const int* in_sizes, int n_in,
                              void* d_out, int out_size, void* d_ws, size_t ws_size,
                              hipStream_t stream) {
    const float* z_ego = (const float*)d_in[0];
    const float* bank  = (const float*)d_in[1];
    const float* svt   = (const float*)d_in[2];
    const float* W     = (const float*)d_in[3];
    float* out = (float*)d_out;
    char* ws = (char*)d_ws;

    if (ws_size >= WS_NEED) {
        float* qn             = (float*)(ws + OFF_QN);
        unsigned short* qnt   = (unsigned short*)(ws + OFF_QNT);
        float* inorm          = (float*)(ws + OFF_INORM);
        float* th             = (float*)(ws + OFF_TH);
        float* gmax           = (float*)(ws + OFF_GMAX);
        unsigned short* bankt = (unsigned short*)(ws + OFF_BANKT);

        qn_prep_kernel<<<B_Q, 256, 0, stream>>>(z_ego, W, qn, qnt);
        prep_bank_kernel<<<NCHUNK, 256, 0, stream>>>(bank, inorm, bankt);
        if (ws_size >= WS_NEED2) {
            float* svtt = (float*)(ws + OFF_SVTT);
            dim3 rg((N_BANK + RT_J - 1) / RT_J, B_Q / RT_Q);   // 98 x 64
            svt_repack_kernel<<<rg, 256, 0, stream>>>(svt, svtt);
            screen5_kernel<<<NSL2 * 4, 256, 0, stream>>>(qnt, bankt, svtt, gmax);
        } else {
            screen4_kernel<<<NSL2 * 4, 256, 0, stream>>>(qnt, bankt, svt, gmax);
        }
        gthresh_kernel<<<B_Q, 256, 0, stream>>>(gmax, th);
        grescore_kernel<<<B_Q, 256, 0, stream>>>(gmax, th, qn, inorm, bank, svt, out);
    } else {
        float* qn    = (float*)(ws + 0);
        float* inorm = (float*)(ws + FB_OFF_INORM);
        float* psc   = (float*)(ws + FB_OFF_PSC);
        int*   pid   = (int*)(ws + FB_OFF_PID);
        fb_qn_kernel<<<B_Q, 256, 0, stream>>>(z_ego, W, qn);
        inorm_kernel<<<(N_BANK + 3) / 4, 256, 0, stream>>>(bank, inorm);
        dim3 grid(FNS, B_Q / FBT);
        fb_score_topk_kernel<<<grid, 256, 0, stream>>>(qn, bank, svt, inorm, psc, pid);
        fb_merge_kernel<<<B_Q, 256, 0, stream>>>(psc, pid, bank, out);
    }
}

// Round 5
// 642.163 us; speedup vs baseline: 1.1397x; 1.0551x over previous
//
#include <hip/hip_runtime.h>
#include <math.h>
#include <stdint.h>

#define B_Q    512
#define N_BANK 100000
#define D_DIM  256
#define K16    16

// ---------------- MFMA path constants ----------------
#define NSL2   256                          // j-slices for screen (grid = NSL2*4)
#define NCHUNK 1563                         // ceil(100000/64)
#define TROW   264                          // bf16 elems per padded row (256 + 8 pad)
#define CHUNK_USHORT (64 * TROW)            // 16896
#define CHUNK_BYTES  (CHUNK_USHORT * 2)     // 33792
#define NGRP   6250                         // 100000 / 16 j-groups per query
#define GSTRIDE 6272                        // padded group row stride (floats)
#define MARGIN 5e-3f                        // >= 2*eps_screen (worst-case bf16 dot bound)
#define CAPG   384                          // max surviving groups per query (exp ~30)
#define NSPLIT 4                            // rescore group-splits per query
#define CAPG_S 96                           // cap per split (CAPG/NSPLIT)
#define GPART  ((NGRP + NSPLIT - 1) / NSPLIT)   // 1563 groups per split

#define SLAB_FLOATS 32768                   // 512 q * 64 j per chunk slab (fp32)

// ws layout (bytes)
#define OFF_QN     0                        // fp32 qn: 512KB
#define OFF_QNT    0x80000                  // bf16 tiled qn: 270336
#define OFF_INORM  0x100000                 // fp32 inorm: 400000
#define OFF_TH     0x170000                 // fp32 th[512]
#define OFF_PKEYS  0x200000                 // u64 pkeys[512][4][16] = 256KB
#define OFF_GMAX   0x400000                 // fp32 gmax[512][6272] = 12.85MB (ends < 0x1400000)
#define OFF_BANKT  0x1400000                // bf16 tiled bank: 1563*33792 (ends 0x465F800)
#define WS_NEED    ((size_t)OFF_BANKT + (size_t)NCHUNK * CHUNK_BYTES)
#define OFF_SVTT   0x4800000                // fp32 chunk-major svt: 1563*131072 = 204.9MB
#define WS_NEED2   ((size_t)OFF_SVTT + (size_t)NCHUNK * SLAB_FLOATS * 4)

// fallback path ws layout
#define FB_OFF_INORM (B_Q * D_DIM * 4)
#define FB_OFF_PSC   (1024 * 1024)
#define FB_OFF_PID   (FB_OFF_PSC + B_Q * 128 * K16 * 4)

typedef __attribute__((ext_vector_type(8))) short short8;
typedef __attribute__((ext_vector_type(4))) float floatx4;

typedef __attribute__((address_space(1))) const unsigned char gu8_t;
typedef __attribute__((address_space(3))) unsigned char lu8_t;

// ---------------- helpers ----------------
__device__ inline unsigned short f2bf(float x) {   // RNE fp32 -> bf16
    unsigned int u = __float_as_uint(x);
    unsigned int r = (u + 0x7FFFu + ((u >> 16) & 1u)) >> 16;
    return (unsigned short)r;
}
__device__ inline unsigned long long pack_key(float s, int idx) {
    unsigned int u = __float_as_uint(s);
    u ^= (u & 0x80000000u) ? 0xFFFFFFFFu : 0x80000000u;  // order-preserving
    return ((unsigned long long)u << 32) | (unsigned int)(~(unsigned int)idx);
}
__device__ inline int key_idx(unsigned long long k) {
    return (int)(~(unsigned int)(k & 0xFFFFFFFFull));
}
__device__ inline unsigned long long shfl_down_u64(unsigned long long x, int off) {
    unsigned int lo = (unsigned int)x;
    unsigned int hi = (unsigned int)(x >> 32);
    lo = __shfl_down(lo, off, 64);
    hi = __shfl_down(hi, off, 64);
    return ((unsigned long long)hi << 32) | lo;
}
__device__ inline unsigned long long shfl_u64(unsigned long long x, int lane) {
    unsigned int lo = (unsigned int)x;
    unsigned int hi = (unsigned int)(x >> 32);
    lo = __shfl(lo, lane, 64);
    hi = __shfl(hi, lane, 64);
    return ((unsigned long long)hi << 32) | lo;
}
__device__ inline unsigned long long umax64(unsigned long long a, unsigned long long b) {
    return a > b ? a : b;
}

// ================= MFMA PATH =================

// qn = normalize(z_ego @ W^T) fp32, plus bf16 padded-tiled copy
__global__ void qn_prep_kernel(const float* __restrict__ z_ego,
                               const float* __restrict__ W,
                               float* __restrict__ qn,
                               unsigned short* __restrict__ qnt) {
    __shared__ float zs[D_DIM];
    __shared__ float red[4];
    int b = blockIdx.x;
    int t = threadIdx.x;
    zs[t] = z_ego[b * D_DIM + t];
    __syncthreads();
    const float4* W4 = reinterpret_cast<const float4*>(W + (size_t)t * D_DIM);
    float acc = 0.f;
#pragma unroll 8
    for (int u = 0; u < 64; ++u) {
        float4 w = W4[u];
        acc += w.x * zs[u * 4 + 0];
        acc += w.y * zs[u * 4 + 1];
        acc += w.z * zs[u * 4 + 2];
        acc += w.w * zs[u * 4 + 3];
    }
    float ss = acc * acc;
#pragma unroll
    for (int off = 32; off > 0; off >>= 1) ss += __shfl_down(ss, off, 64);
    if ((t & 63) == 0) red[t >> 6] = ss;
    __syncthreads();
    float tot = red[0] + red[1] + red[2] + red[3];
    float n = fmaxf(sqrtf(tot), 1e-12f);
    float v = acc / n;
    qn[b * D_DIM + t] = v;
    qnt[(size_t)(b >> 6) * CHUNK_USHORT + (size_t)(b & 63) * TROW + t] = f2bf(v);
}

// fused: row norms + bf16 normalized tiled bank
__global__ __launch_bounds__(256)
void prep_bank_kernel(const float* __restrict__ bank,
                      float* __restrict__ inorm,
                      unsigned short* __restrict__ bankt) {
    int c = blockIdx.x;
    int t = threadIdx.x, w = t >> 6, l = t & 63;
    unsigned short* dst = bankt + (size_t)c * CHUNK_USHORT;
#pragma unroll 1
    for (int rr = 0; rr < 16; ++rr) {
        int row = w * 16 + rr;
        int jg = c * 64 + row;
        ushort4 o = {0, 0, 0, 0};
        if (jg < N_BANK) {
            float4 v = *reinterpret_cast<const float4*>(bank + (size_t)jg * D_DIM + l * 4);
            float ss = v.x * v.x + v.y * v.y + v.z * v.z + v.w * v.w;
#pragma unroll
            for (int off = 1; off < 64; off <<= 1) ss += __shfl_xor(ss, off, 64);
            float inv = 1.0f / fmaxf(sqrtf(ss), 1e-12f);
            o.x = f2bf(v.x * inv); o.y = f2bf(v.y * inv);
            o.z = f2bf(v.z * inv); o.w = f2bf(v.w * inv);
            if (l == 0) inorm[jg] = inv;
        }
        *reinterpret_cast<ushort4*>(dst + (size_t)row * TROW + l * 4) = o;
    }
}

// svt tiled transpose: [q][j] -> svtt[c][q][64 j'], fp32 (bit-identical values).
#define RT_Q 8
#define RT_J 1024
__global__ __launch_bounds__(256)
void svt_repack_kernel(const float* __restrict__ svt,
                       float* __restrict__ svtt) {
    __shared__ float tile[RT_Q][RT_J + 4];
    int t = threadIdx.x;
    int jt = blockIdx.x;                 // j-tile (0..97)
    int q0 = blockIdx.y * RT_Q;          // 0..504
    int jl = t * 4;                      // 0..1020
#pragma unroll
    for (int qq = 0; qq < RT_Q; ++qq) {
        int j = jt * RT_J + jl;
        float4 v = make_float4(0.f, 0.f, 0.f, 0.f);
        if (j < N_BANK)                  // N_BANK % 4 == 0 -> full float4 valid
            v = *reinterpret_cast<const float4*>(svt + (size_t)(q0 + qq) * N_BANK + j);
        *reinterpret_cast<float4*>(&tile[qq][jl]) = v;
    }
    __syncthreads();
    int half = t >> 7;                   // 2 chunks per pass
    int q1 = (t >> 4) & 7;
    int m = t & 15;
#pragma unroll
    for (int p = 0; p < 8; ++p) {
        int cc = p * 2 + half;
        int c = jt * 16 + cc;
        if (c < NCHUNK) {
            float4 v = *reinterpret_cast<const float4*>(&tile[q1][cc * 64 + m * 4]);
            *reinterpret_cast<float4*>(svtt + (size_t)c * SLAB_FLOATS
                                       + (size_t)(q0 + q1) * 64 + m * 4) = v;
        }
    }
}

// screen5: MFMA screen reading svt from the chunk-major repacked slab.
__global__ __launch_bounds__(256, 4)
void screen5_kernel(const unsigned short* __restrict__ qnt,
                    const unsigned short* __restrict__ bankt,
                    const float* __restrict__ svtt,
                    float* __restrict__ gmax) {
    __shared__ unsigned short lbank[CHUNK_USHORT];   // 33792 B
    int t = threadIdx.x, w = t >> 6, l = t & 63;
    int lane16 = l & 15, quad = l >> 4;

    int bid = blockIdx.x;
    int xcd = bid & 7;
    int i = bid >> 3;                    // 0..127
    int slice = (xcd << 5) + (i >> 2);   // 0..255
    int qb = i & 3;                      // q-block 0..3 (128 queries each)

    int qt = qb * 4 + w;                 // this wave's 32-query tile (0..15)
    int qbase = qt * 32;

    short8 afrag[2][8];
    {
        const unsigned short* abase = qnt + (size_t)(qt >> 1) * CHUNK_USHORT
                                          + (size_t)((qt & 1) * 32) * TROW;
#pragma unroll
        for (int s = 0; s < 2; ++s)
#pragma unroll
            for (int k = 0; k < 8; ++k)
                afrag[s][k] = *reinterpret_cast<const short8*>(
                    abase + (size_t)(16 * s + lane16) * TROW + k * 32 + quad * 8);
    }

    const float* sp[2][4];
#pragma unroll
    for (int s = 0; s < 2; ++s)
#pragma unroll
        for (int r = 0; r < 4; ++r)
            sp[s][r] = svtt + (size_t)(qbase + 16 * s + 4 * quad + r) * 64 + lane16;

    for (int c = slice; c < NCHUNK; c += NSL2) {
        int j0 = c * 64;

        {
            const unsigned char* gsrc = (const unsigned char*)bankt + (size_t)c * CHUNK_BYTES;
            unsigned char* lbase = (unsigned char*)lbank;
#pragma unroll
            for (int i2 = 0; i2 < 8; ++i2) {
                int off = i2 * 4096 + w * 1024;
                __builtin_amdgcn_global_load_lds((gu8_t*)(gsrc + off + l * 16),
                                                 (lu8_t*)(lbase + off), 16, 0, 0);
            }
            int off8 = 32768 + w * 256;  // tail 1024B, 4B per lane
            __builtin_amdgcn_global_load_lds((gu8_t*)(gsrc + off8 + l * 4),
                                             (lu8_t*)(lbase + off8), 4, 0, 0);
        }

        float sv[4][2][4];
        {
            size_t slabOff = (size_t)c * SLAB_FLOATS;
#pragma unroll
            for (int s = 0; s < 2; ++s)
#pragma unroll
                for (int r = 0; r < 4; ++r) {
                    const float* rp = sp[s][r] + slabOff;
#pragma unroll
                    for (int jg = 0; jg < 4; ++jg)
                        sv[jg][s][r] = rp[16 * jg];
                }
        }

        __syncthreads();   // staging + svt complete

        int g0 = c * 4;
#pragma unroll
        for (int jg = 0; jg < 4; ++jg) {
            floatx4 acc0 = (floatx4){0.f, 0.f, 0.f, 0.f};
            floatx4 acc1 = (floatx4){0.f, 0.f, 0.f, 0.f};
            const unsigned short* bbase = lbank + (size_t)(16 * jg + lane16) * TROW + quad * 8;
#pragma unroll
            for (int k = 0; k < 8; ++k) {
                short8 bfrag = *reinterpret_cast<const short8*>(bbase + k * 32);
                acc0 = __builtin_amdgcn_mfma_f32_16x16x32_bf16(afrag[0][k], bfrag, acc0, 0, 0, 0);
                acc1 = __builtin_amdgcn_mfma_f32_16x16x32_bf16(afrag[1][k], bfrag, acc1, 0, 0, 0);
            }

            int jglob = j0 + 16 * jg + lane16;
            bool inb = jglob < N_BANK;
            int g = g0 + jg;
            bool doStore = (lane16 == 0) && (g < NGRP);
#pragma unroll
            for (int s = 0; s < 2; ++s) {
#pragma unroll
                for (int r = 0; r < 4; ++r) {
                    float a = (s == 0) ? acc0[r] : acc1[r];
                    float score = inb ? (0.5f * a + 0.5f * sv[jg][s][r]) : -INFINITY;
                    score = fmaxf(score, __shfl_xor(score, 1, 64));
                    score = fmaxf(score, __shfl_xor(score, 2, 64));
                    score = fmaxf(score, __shfl_xor(score, 4, 64));
                    score = fmaxf(score, __shfl_xor(score, 8, 64));
                    if (doStore) {
                        int q = qbase + 16 * s + 4 * quad + r;
                        gmax[(size_t)q * GSTRIDE + g] = score;
                    }
                }
            }
        }
        __syncthreads();   // protect lbank before next chunk's staging
    }
}

// screen4 (tier-2, kept verbatim): direct scattered svt reads
__global__ __launch_bounds__(256, 4)
void screen4_kernel(const unsigned short* __restrict__ qnt,
                    const unsigned short* __restrict__ bankt,
                    const float* __restrict__ svt,
                    float* __restrict__ gmax) {
    __shared__ unsigned short lbank[CHUNK_USHORT];   // 33792 B
    int t = threadIdx.x, w = t >> 6, l = t & 63;
    int lane16 = l & 15, quad = l >> 4;

    int bid = blockIdx.x;
    int xcd = bid & 7;
    int i = bid >> 3;
    int slice = (xcd << 5) + (i >> 2);
    int qb = i & 3;

    int qt = qb * 4 + w;
    int qbase = qt * 32;

    short8 afrag[2][8];
    {
        const unsigned short* abase = qnt + (size_t)(qt >> 1) * CHUNK_USHORT
                                          + (size_t)((qt & 1) * 32) * TROW;
#pragma unroll
        for (int s = 0; s < 2; ++s)
#pragma unroll
            for (int k = 0; k < 8; ++k)
                afrag[s][k] = *reinterpret_cast<const short8*>(
                    abase + (size_t)(16 * s + lane16) * TROW + k * 32 + quad * 8);
    }

    const float* svr[2][4];
#pragma unroll
    for (int s = 0; s < 2; ++s)
#pragma unroll
        for (int r = 0; r < 4; ++r)
            svr[s][r] = svt + (size_t)(qbase + 16 * s + 4 * quad + r) * (size_t)N_BANK;

    for (int c = slice; c < NCHUNK; c += NSL2) {
        int j0 = c * 64;
        {
            const unsigned char* gsrc = (const unsigned char*)bankt + (size_t)c * CHUNK_BYTES;
            unsigned char* lbase = (unsigned char*)lbank;
#pragma unroll
            for (int i2 = 0; i2 < 8; ++i2) {
                int off = i2 * 4096 + w * 1024;
                __builtin_amdgcn_global_load_lds((gu8_t*)(gsrc + off + l * 16),
                                                 (lu8_t*)(lbase + off), 16, 0, 0);
            }
            int off8 = 32768 + w * 256;
            __builtin_amdgcn_global_load_lds((gu8_t*)(gsrc + off8 + l * 4),
                                             (lu8_t*)(lbase + off8), 4, 0, 0);
        }

        float sv[4][2][4];
#pragma unroll
        for (int s = 0; s < 2; ++s)
#pragma unroll
            for (int r = 0; r < 4; ++r) {
                const float* rp = svr[s][r] + j0 + lane16;
#pragma unroll
                for (int jg = 0; jg < 4; ++jg) {
                    int jglob = j0 + 16 * jg + lane16;
                    sv[jg][s][r] = (jglob < N_BANK) ? rp[16 * jg] : 0.f;
                }
            }

        __syncthreads();

        int g0 = c * 4;
#pragma unroll
        for (int jg = 0; jg < 4; ++jg) {
            floatx4 acc0 = (floatx4){0.f, 0.f, 0.f, 0.f};
            floatx4 acc1 = (floatx4){0.f, 0.f, 0.f, 0.f};
            const unsigned short* bbase = lbank + (size_t)(16 * jg + lane16) * TROW + quad * 8;
#pragma unroll
            for (int k = 0; k < 8; ++k) {
                short8 bfrag = *reinterpret_cast<const short8*>(bbase + k * 32);
                acc0 = __builtin_amdgcn_mfma_f32_16x16x32_bf16(afrag[0][k], bfrag, acc0, 0, 0, 0);
                acc1 = __builtin_amdgcn_mfma_f32_16x16x32_bf16(afrag[1][k], bfrag, acc1, 0, 0, 0);
            }

            int jglob = j0 + 16 * jg + lane16;
            bool inb = jglob < N_BANK;
            int g = g0 + jg;
            bool doStore = (lane16 == 0) && (g < NGRP);
#pragma unroll
            for (int s = 0; s < 2; ++s) {
#pragma unroll
                for (int r = 0; r < 4; ++r) {
                    float a = (s == 0) ? acc0[r] : acc1[r];
                    float score = inb ? (0.5f * a + 0.5f * sv[jg][s][r]) : -INFINITY;
                    score = fmaxf(score, __shfl_xor(score, 1, 64));
                    score = fmaxf(score, __shfl_xor(score, 2, 64));
                    score = fmaxf(score, __shfl_xor(score, 4, 64));
                    score = fmaxf(score, __shfl_xor(score, 8, 64));
                    if (doStore) {
                        int q = qbase + 16 * s + 4 * quad + r;
                        gmax[(size_t)q * GSTRIDE + g] = score;
                    }
                }
            }
        }
        __syncthreads();
    }
}

// per-query: 16th-largest group-max - margin -> th
__global__ __launch_bounds__(256)
void gthresh_kernel(const float* __restrict__ gmax,
                    float* __restrict__ th) {
    __shared__ float buf[NGRP];    // 25 KB
    __shared__ float red[4];
    int q = blockIdx.x, t = threadIdx.x, w = t >> 6;
    for (int i = t; i < NGRP; i += 256) buf[i] = gmax[(size_t)q * GSTRIDE + i];
    __syncthreads();
    float s16 = -INFINITY;
    for (int r = 0; r < K16; ++r) {
        float m = -INFINITY;
        for (int i = t; i < NGRP; i += 256) m = fmaxf(m, buf[i]);
#pragma unroll
        for (int off = 32; off > 0; off >>= 1) m = fmaxf(m, __shfl_down(m, off, 64));
        if ((t & 63) == 0) red[w] = m;
        __syncthreads();
        m = fmaxf(fmaxf(red[0], red[1]), fmaxf(red[2], red[3]));
        if (r == K16 - 1) s16 = m;
        if (r < K16 - 1) {
            for (int i = t; i < NGRP; i += 256)
                if (buf[i] == m) buf[i] = -INFINITY;
        }
        __syncthreads();
    }
    if (t == 0) th[q] = s16 - MARGIN;
}

// gscore: per (split, query) block — collect surviving groups in this split's
// g-range, exact fp32 rescore (bit-identical 64-lane dot association),
// 4-way pipelined scattered row loads, local top-16 -> pkeys[q][split][16].
__global__ __launch_bounds__(256)
void gscore_kernel(const float* __restrict__ gmax,
                   const float* __restrict__ th,
                   const float* __restrict__ qn,
                   const float* __restrict__ inorm,
                   const float* __restrict__ bank,
                   const float* __restrict__ svt,
                   unsigned long long* __restrict__ pkeys) {
    __shared__ float qns[D_DIM];
    __shared__ int glist[CAPG_S];
    __shared__ unsigned long long keys2[CAPG_S * K16];   // 12 KB
    __shared__ unsigned long long wred[4];
    __shared__ int gcntS;
    int s = blockIdx.x;                  // split 0..NSPLIT-1
    int b = blockIdx.y;                  // query
    int t = threadIdx.x, w = t >> 6, l = t & 63;

    qns[t] = qn[(size_t)b * D_DIM + t];
    if (t == 0) gcntS = 0;
    __syncthreads();
    float thb = th[b];
    int ga = s * GPART;
    int gb = ga + GPART < NGRP ? ga + GPART : NGRP;
    for (int g = ga + t; g < gb; g += 256) {
        if (gmax[(size_t)b * GSTRIDE + g] >= thb) {
            int p = atomicAdd(&gcntS, 1);
            if (p < CAPG_S) glist[p] = g;
        }
    }
    __syncthreads();
    int ng = gcntS < CAPG_S ? gcntS : CAPG_S;
    int ncand = ng * K16;

    const float4* bank4 = reinterpret_cast<const float4*>(bank);
    float4 qv = reinterpret_cast<const float4*>(qns)[l];
    // 4-way pipelined candidate scoring (4 scattered 1KB rows in flight/wave);
    // per-candidate reduction order identical to the original grescore.
    for (int ci = w; ci < ncand; ci += 16) {
        int j[4]; bool has[4];
#pragma unroll
        for (int p = 0; p < 4; ++p) {
            int c2 = ci + 4 * p;
            has[p] = c2 < ncand;
            int cs = has[p] ? c2 : ci;
            j[p] = glist[cs >> 4] * K16 + (cs & 15);
        }
        float inv[4], sva[4];
        if (l == 0) {
#pragma unroll
            for (int p = 0; p < 4; ++p)
                if (has[p]) { inv[p] = inorm[j[p]]; sva[p] = svt[(size_t)b * N_BANK + j[p]]; }
        }
        float4 bv[4];
#pragma unroll
        for (int p = 0; p < 4; ++p) bv[p] = bank4[(size_t)j[p] * 64 + l];
#pragma unroll
        for (int p = 0; p < 4; ++p) {
            float d = qv.x * bv[p].x + qv.y * bv[p].y + qv.z * bv[p].z + qv.w * bv[p].w;
#pragma unroll
            for (int off = 32; off > 0; off >>= 1) d += __shfl_down(d, off, 64);
            if (l == 0 && has[p]) {
                float sc = 0.5f * (d * inv[p]) + 0.5f * sva[p];
                keys2[ci + 4 * p] = pack_key(sc, j[p]);
            }
        }
    }
    __syncthreads();

    unsigned long long* outk = pkeys + ((size_t)b * NSPLIT + s) * K16;
    for (int r = 0; r < K16; ++r) {
        unsigned long long best = 0ull;
        for (int i2 = t; i2 < ncand; i2 += 256) best = umax64(best, keys2[i2]);
#pragma unroll
        for (int off = 32; off > 0; off >>= 1) best = umax64(best, shfl_down_u64(best, off));
        if (l == 0) wred[w] = best;
        __syncthreads();
        unsigned long long W = umax64(umax64(wred[0], wred[1]), umax64(wred[2], wred[3]));
        if (t == 0) outk[r] = W;
        for (int i2 = t; i2 < ncand; i2 += 256)
            if (keys2[i2] == W) keys2[i2] = 0ull;
        __syncthreads();
    }
}

// gmerge: top-16 of the NSPLIT*16 per-split keys (contains the exact global
// top-16; keys unique -> deterministic), then index write + gather.
__global__ __launch_bounds__(256)
void gmerge_kernel(const unsigned long long* __restrict__ pkeys,
                   const float* __restrict__ bank,
                   float* __restrict__ out) {
    __shared__ int winI[K16];
    int b = blockIdx.x, t = threadIdx.x;
    if (t < 64) {
        unsigned long long k = pkeys[(size_t)b * (NSPLIT * K16) + t];
        for (int r = 0; r < K16; ++r) {
            unsigned long long m = k;
#pragma unroll
            for (int off = 32; off > 0; off >>= 1) m = umax64(m, shfl_down_u64(m, off));
            m = shfl_u64(m, 0);
            if (t == 0) winI[r] = key_idx(m);
            if (k == m) k = 0ull;
        }
    }
    __syncthreads();
    if (t < K16)
        out[(size_t)B_Q * K16 * D_DIM + (size_t)b * K16 + t] = (float)winI[t];
    const float4* bank4 = reinterpret_cast<const float4*>(bank);
    float4* out4 = reinterpret_cast<float4*>(out);
    for (int u = t; u < K16 * 64; u += 256) {
        int r = u >> 6, cc = u & 63;
        out4[((size_t)b * K16 + r) * 64 + cc] = bank4[(size_t)winI[r] * 64 + cc];
    }
}

// ================= FALLBACK (verified round-1) PATH =================
#define FBT 64
#define FJT 64
#define FKC 64
#define FNS 128
#define FNC ((N_BANK + FJT - 1) / FJT)

__global__ void inorm_kernel(const float* __restrict__ bank,
                             float* __restrict__ inorm) {
    int w = threadIdx.x >> 6;
    int lane = threadIdx.x & 63;
    int j = blockIdx.x * 4 + w;
    if (j >= N_BANK) return;
    const float4* r4 = reinterpret_cast<const float4*>(bank + (size_t)j * D_DIM);
    float4 v = r4[lane];
    float ss = v.x * v.x + v.y * v.y + v.z * v.z + v.w * v.w;
#pragma unroll
    for (int off = 32; off > 0; off >>= 1) ss += __shfl_down(ss, off, 64);
    if (lane == 0) inorm[j] = 1.0f / fmaxf(sqrtf(ss), 1e-12f);
}

__global__ void fb_qn_kernel(const float* __restrict__ z_ego,
                             const float* __restrict__ W,
                             float* __restrict__ qn) {
    __shared__ float zs[D_DIM];
    __shared__ float red[4];
    int b = blockIdx.x;
    int t = threadIdx.x;
    zs[t] = z_ego[b * D_DIM + t];
    __syncthreads();
    const float4* W4 = reinterpret_cast<const float4*>(W + (size_t)t * D_DIM);
    float acc = 0.f;
#pragma unroll 8
    for (int u = 0; u < 64; ++u) {
        float4 w = W4[u];
        acc += w.x * zs[u * 4 + 0]; acc += w.y * zs[u * 4 + 1];
        acc += w.z * zs[u * 4 + 2]; acc += w.w * zs[u * 4 + 3];
    }
    float ss = acc * acc;
#pragma unroll
    for (int off = 32; off > 0; off >>= 1) ss += __shfl_down(ss, off, 64);
    if ((t & 63) == 0) red[t >> 6] = ss;
    __syncthreads();
    float tot = red[0] + red[1] + red[2] + red[3];
    qn[b * D_DIM + t] = acc / fmaxf(sqrtf(tot), 1e-12f);
}

__global__ __launch_bounds__(256)
void fb_score_topk_kernel(const float* __restrict__ qn,
                          const float* __restrict__ bank,
                          const float* __restrict__ svt,
                          const float* __restrict__ inorm,
                          float* __restrict__ psc,
                          int* __restrict__ pid) {
    __shared__ float As[FKC][FBT];
    __shared__ float Bsh[FKC][FJT];
    __shared__ float Ss[FBT][FJT + 1];
    int slice = blockIdx.x;
    int qbase = blockIdx.y * FBT;
    int t = threadIdx.x;
    int tq = t >> 4, tj = t & 15;
    int q0 = tq * 4, j0l = tj * 4;
    float sc[K16]; int id[K16];
#pragma unroll
    for (int i = 0; i < K16; ++i) { sc[i] = -INFINITY; id[i] = 0x7fffffff; }
    for (int c = slice; c < FNC; c += FNS) {
        int j0 = c * FJT;
        float acc[4][4];
#pragma unroll
        for (int a = 0; a < 4; ++a)
#pragma unroll
            for (int b2 = 0; b2 < 4; ++b2) acc[a][b2] = 0.f;
        for (int kc = 0; kc < D_DIM; kc += FKC) {
            __syncthreads();
#pragma unroll
            for (int r = 0; r < 4; ++r) {
                int idx = t + 256 * r;
                int q = idx & 63, kv = idx >> 6;
                float4 v = *reinterpret_cast<const float4*>(
                    &qn[(size_t)(qbase + q) * D_DIM + kc + kv * 4]);
                As[kv * 4 + 0][q] = v.x; As[kv * 4 + 1][q] = v.y;
                As[kv * 4 + 2][q] = v.z; As[kv * 4 + 3][q] = v.w;
            }
#pragma unroll
            for (int r = 0; r < 4; ++r) {
                int idx = t + 256 * r;
                int j = idx & 63, kv = idx >> 6;
                int jg = j0 + j;
                float4 v = make_float4(0.f, 0.f, 0.f, 0.f);
                if (jg < N_BANK)
                    v = *reinterpret_cast<const float4*>(
                        &bank[(size_t)jg * D_DIM + kc + kv * 4]);
                Bsh[kv * 4 + 0][j] = v.x; Bsh[kv * 4 + 1][j] = v.y;
                Bsh[kv * 4 + 2][j] = v.z; Bsh[kv * 4 + 3][j] = v.w;
            }
            __syncthreads();
#pragma unroll
            for (int k = 0; k < FKC; ++k) {
                float4 av = *reinterpret_cast<const float4*>(&As[k][q0]);
                float4 bv = *reinterpret_cast<const float4*>(&Bsh[k][j0l]);
                float a[4] = {av.x, av.y, av.z, av.w};
                float bb[4] = {bv.x, bv.y, bv.z, bv.w};
#pragma unroll
                for (int qi = 0; qi < 4; ++qi)
#pragma unroll
                    for (int ji = 0; ji < 4; ++ji) acc[qi][ji] += a[qi] * bb[ji];
            }
        }
        bool full = (j0 + FJT <= N_BANK);
        if (full) {
            float4 inv = *reinterpret_cast<const float4*>(&inorm[j0 + j0l]);
            float iv[4] = {inv.x, inv.y, inv.z, inv.w};
#pragma unroll
            for (int qi = 0; qi < 4; ++qi) {
                int q = qbase + q0 + qi;
                float4 svv = *reinterpret_cast<const float4*>(
                    &svt[(size_t)q * N_BANK + j0 + j0l]);
                float s[4] = {svv.x, svv.y, svv.z, svv.w};
#pragma unroll
                for (int ji = 0; ji < 4; ++ji)
                    Ss[q0 + qi][j0l + ji] = 0.5f * (acc[qi][ji] * iv[ji]) + 0.5f * s[ji];
            }
        } else {
#pragma unroll
            for (int qi = 0; qi < 4; ++qi) {
                int q = qbase + q0 + qi;
#pragma unroll
                for (int ji = 0; ji < 4; ++ji) {
                    int jg = j0 + j0l + ji;
                    float s = -INFINITY;
                    if (jg < N_BANK)
                        s = 0.5f * (acc[qi][ji] * inorm[jg]) + 0.5f * svt[(size_t)q * N_BANK + jg];
                    Ss[q0 + qi][j0l + ji] = s;
                }
            }
        }
        __syncthreads();
        if (t < FBT) {
#pragma unroll 1
            for (int jj = 0; jj < FJT; ++jj) {
                int jg = j0 + jj;
                if (jg >= N_BANK) break;
                float s = Ss[t][jj];
                if (s > sc[K16 - 1] || (s == sc[K16 - 1] && jg < id[K16 - 1])) {
                    float cs = s; int ci = jg;
#pragma unroll
                    for (int i = 0; i < K16; ++i) {
                        bool bt2 = (cs > sc[i]) || (cs == sc[i] && ci < id[i]);
                        float ts = sc[i]; int ti = id[i];
                        if (bt2) { sc[i] = cs; id[i] = ci; cs = ts; ci = ti; }
                    }
                }
            }
        }
    }
    if (t < FBT) {
        int q = qbase + t;
        size_t base = ((size_t)q * FNS + slice) * K16;
#pragma unroll
        for (int i = 0; i < K16; ++i) { psc[base + i] = sc[i]; pid[base + i] = id[i]; }
    }
}

__global__ __launch_bounds__(256)
void fb_merge_kernel(const float* __restrict__ psc,
                     const int* __restrict__ pid,
                     const float* __restrict__ bank,
                     float* __restrict__ out) {
    __shared__ unsigned long long keys[FNS * K16];
    __shared__ unsigned long long wred[4];
    __shared__ int win[K16];
    int b = blockIdx.x, t = threadIdx.x;
    for (int i = t; i < FNS * K16; i += 256) {
        float s = psc[(size_t)b * FNS * K16 + i];
        unsigned int u = __float_as_uint(s);
        u ^= (u & 0x80000000u) ? 0xFFFFFFFFu : 0x80000000u;
        unsigned int iv = ~(unsigned int)pid[(size_t)b * FNS * K16 + i];
        keys[i] = ((unsigned long long)u << 32) | iv;
    }
    __syncthreads();
    for (int r = 0; r < K16; ++r) {
        unsigned long long best = 0ull;
        for (int i = t; i < FNS * K16; i += 256) best = umax64(best, keys[i]);
#pragma unroll
        for (int off = 32; off > 0; off >>= 1) best = umax64(best, shfl_down_u64(best, off));
        if ((t & 63) == 0) wred[t >> 6] = best;
        __syncthreads();
        unsigned long long w = umax64(umax64(wred[0], wred[1]), umax64(wred[2], wred[3]));
        if (t == 0) win[r] = (int)(~(unsigned int)w);
        for (int i = t; i < FNS * K16; i += 256)
            if (keys[i] == w) keys[i] = 0ull;
        __syncthreads();
    }
    if (t < K16)
        out[(size_t)B_Q * K16 * D_DIM + (size_t)b * K16 + t] = (float)win[t];
    const float4* bank4 = reinterpret_cast<const float4*>(bank);
    float4* out4 = reinterpret_cast<float4*>(out);
    for (int u = t; u < K16 * 64; u += 256) {
        int r = u >> 6, c = u & 63;
        out4[((size_t)b * K16 + r) * 64 + c] = bank4[(size_t)win[r] * 64 + c];
    }
}

// ---------------- launcher ----------------
extern "C" void kernel_launch(void* const* d_in, const int* in_sizes, int n_in,
                              void* d_out, int out_size, void* d_ws, size_t ws_size,
                              hipStream_t stream) {
    const float* z_ego = (const float*)d_in[0];
    const float* bank  = (const float*)d_in[1];
    const float* svt   = (const float*)d_in[2];
    const float* W     = (const float*)d_in[3];
    float* out = (float*)d_out;
    char* ws = (char*)d_ws;

    if (ws_size >= WS_NEED) {
        float* qn             = (float*)(ws + OFF_QN);
        unsigned short* qnt   = (unsigned short*)(ws + OFF_QNT);
        float* inorm          = (float*)(ws + OFF_INORM);
        float* th             = (float*)(ws + OFF_TH);
        unsigned long long* pkeys = (unsigned long long*)(ws + OFF_PKEYS);
        float* gmax           = (float*)(ws + OFF_GMAX);
        unsigned short* bankt = (unsigned short*)(ws + OFF_BANKT);

        qn_prep_kernel<<<B_Q, 256, 0, stream>>>(z_ego, W, qn, qnt);
        prep_bank_kernel<<<NCHUNK, 256, 0, stream>>>(bank, inorm, bankt);
        if (ws_size >= WS_NEED2) {
            float* svtt = (float*)(ws + OFF_SVTT);
            dim3 rg((N_BANK + RT_J - 1) / RT_J, B_Q / RT_Q);   // 98 x 64
            svt_repack_kernel<<<rg, 256, 0, stream>>>(svt, svtt);
            screen5_kernel<<<NSL2 * 4, 256, 0, stream>>>(qnt, bankt, svtt, gmax);
        } else {
            screen4_kernel<<<NSL2 * 4, 256, 0, stream>>>(qnt, bankt, svt, gmax);
        }
        gthresh_kernel<<<B_Q, 256, 0, stream>>>(gmax, th);
        dim3 sg(NSPLIT, B_Q);
        gscore_kernel<<<sg, 256, 0, stream>>>(gmax, th, qn, inorm, bank, svt, pkeys);
        gmerge_kernel<<<B_Q, 256, 0, stream>>>(pkeys, bank, out);
    } else {
        float* qn    = (float*)(ws + 0);
        float* inorm = (float*)(ws + FB_OFF_INORM);
        float* psc   = (float*)(ws + FB_OFF_PSC);
        int*   pid   = (int*)(ws + FB_OFF_PID);
        fb_qn_kernel<<<B_Q, 256, 0, stream>>>(z_ego, W, qn);
        inorm_kernel<<<(N_BANK + 3) / 4, 256, 0, stream>>>(bank, inorm);
        dim3 grid(FNS, B_Q / FBT);
        fb_score_topk_kernel<<<grid, 256, 0, stream>>>(qn, bank, svt, inorm, psc, pid);
        fb_merge_kernel<<<B_Q, 256, 0, stream>>>(psc, pid, bank, out);
    }
}